// Round 21
// baseline (240.950 us; speedup 1.0000x reference)
//
#include <hip/hip_runtime.h>

#define NPTS 8192
#define KNN  20
#define NREP 64
#define FCAP 256

__device__ __forceinline__ float pair_dist4(float qx, float qy, float qz, float xxn, float4 c) {
    float dot = fmaf(qz, c.z, fmaf(qy, c.y, qx * c.x));
    return fmaf(2.f, dot, -xxn) - c.w;
}
__device__ __forceinline__ float self_sq(float dx, float dy, float dz) {
    return fmaf(dz, dz, fmaf(dy, dy, dx * dx));
}
__device__ __forceinline__ float lrelu(float v) { return (v >= 0.f) ? v : 0.2f * v; }

__device__ __forceinline__ void compute_affine(const float* __restrict__ gs,
                                               const float* __restrict__ g,
                                               const float* __restrict__ b,
                                               float* saff, int tid) {
    if (tid < 64) {
        float s = 0.f, ss = 0.f;
        for (int r = 0; r < NREP; ++r) { s += gs[r * 128 + tid]; ss += gs[r * 128 + 64 + tid]; }
        const float invM = 1.f / (float)(NPTS * KNN);
        float mean = s * invM;
        float var = ss * invM - mean * mean;
        float sc = g[tid] * rsqrtf(var + 1e-5f);
        saff[tid] = sc;
        saff[64 + tid] = b[tid] - mean * sc;
    }
}

// ---------------------------------------------------------------- prep (+ fused stage-1 proj)
// blocks [0,360): pk pack, Wt3/Wt5/W9at/W9bt transposes, gsAll zero.
// blocks [360,1384): stage-1 projection reading W1 directly (bit-identical fmaf order).
__global__ __launch_bounds__(256) void prep_proj_kernel(const float* __restrict__ x,
                                                        const float* __restrict__ W1,
                                                        const float* __restrict__ W3,
                                                        const float* __restrict__ W5,
                                                        const float* __restrict__ W9a,
                                                        const float* __restrict__ W9b,
                                                        float4* __restrict__ pk,
                                                        float* __restrict__ Wt3,
                                                        float* __restrict__ Wt5,
                                                        float* __restrict__ W9at,
                                                        float* __restrict__ W9bt,
                                                        float* __restrict__ gsAll,
                                                        float* __restrict__ P) {
    int tid = threadIdx.x;
    if (blockIdx.x >= 360) {
        int bb = blockIdx.x - 360;
        int o = tid & 127, h = tid >> 7;
        int n0 = bb * 8 + h * 4;
        float acc[4] = {0.f, 0.f, 0.f, 0.f};
        const float* wrow = (o < 64) ? (W1 + o * 134) : (W1 + (o - 64) * 134 + 67);
        for (int c = 0; c < 67; ++c) {
            float w = wrow[c];
#pragma unroll
            for (int i = 0; i < 4; ++i) acc[i] = fmaf(x[(n0 + i) + c * NPTS], w, acc[i]);
        }
#pragma unroll
        for (int i = 0; i < 4; ++i) P[(n0 + i) * 128 + o] = acc[i];
        return;
    }
    int gid = blockIdx.x * 256 + tid;
    if (gid < NPTS) {
        float dx = x[64 * NPTS + gid], dy = x[65 * NPTS + gid], dz = x[66 * NPTS + gid];
        pk[gid] = make_float4(dx, dy, dz, self_sq(dx, dy, dz));
        return;
    }
    gid -= NPTS;
    if (gid < 64 * 128) {
        int c = gid >> 7, o = gid & 127;
        Wt3[gid] = (o < 64) ? W3[o * 128 + c] : W3[(o - 64) * 128 + 64 + c];
        return;
    }
    gid -= 64 * 128;
    if (gid < 64 * 128) {
        int c = gid >> 7, o = gid & 127;
        Wt5[gid] = (o < 64) ? W5[o * 128 + c] : W5[(o - 64) * 128 + 64 + c];
        return;
    }
    gid -= 64 * 128;
    if (gid < 192 * 128) {
        int c = gid >> 7, j = gid & 127;
        W9at[gid] = W9a[j * 192 + c];
        return;
    }
    gid -= 192 * 128;
    if (gid < 128 * 16) {
        int c = gid >> 4, j = gid & 15;
        W9bt[gid] = W9b[j * 128 + c];
        return;
    }
    gid -= 128 * 16;
    if (gid < 5 * NREP * 128) gsAll[gid] = 0.f;
}

// ---------------------------------------------------------------- fused theta + filter + select + zsum1
// 4 queries/block, 1 query/wave. Theta derived in-kernel from chunks 0-1 (2048-pt subset).
__global__ __launch_bounds__(256) void knn_fsel(const float4* __restrict__ pk,
                                                int* __restrict__ idx_out,
                                                const float* __restrict__ P,
                                                float* __restrict__ gs) {
    __shared__ float4 cpt[1024];
    __shared__ int bufi[4][FCAP];
    int tid = threadIdx.x, wid = tid >> 6, lane = tid & 63;
    int q = blockIdx.x * 4 + wid;
    float4 qp = pk[q];
    unsigned long long below = (1ull << lane) - 1ull;

    // pass A: per-lane max over the 2048-point subset (chunks 0,1; disjoint lane sets)
    float mv = -INFINITY;
    for (int ch = 0; ch < 2; ++ch) {
        __syncthreads();
        for (int i = tid; i < 1024; i += 256) cpt[i] = pk[ch * 1024 + i];
        __syncthreads();
        for (int t = 0; t < 16; ++t)
            mv = fmaxf(mv, pair_dist4(qp.x, qp.y, qp.z, qp.w, cpt[t * 64 + lane]));
    }
    // theta = 20th largest of 64 disjoint lane maxima => theta <= v20(full set)
    float sel = mv, th = -INFINITY;
    for (int r = 0; r < KNN; ++r) {
        float v = sel;
#pragma unroll
        for (int m = 32; m >= 1; m >>= 1) v = fmaxf(v, __shfl_xor(v, m));
        th = v;
        unsigned long long bm = __ballot(sel == v);
        if (lane == __ffsll(bm) - 1) sel = -INFINITY;
    }
    th -= 1e-3f;

    // pass B: filter all 8 chunks; register-wcnt compaction
    int wcnt = 0;
    for (int ch = 0; ch < 8; ++ch) {
        __syncthreads();
        for (int i = tid; i < 1024; i += 256) cpt[i] = pk[ch * 1024 + i];
        __syncthreads();
        for (int t = 0; t < 16; ++t) {
            int gi = ch * 1024 + t * 64 + lane;
            float4 c = cpt[t * 64 + lane];
            float d = pair_dist4(qp.x, qp.y, qp.z, qp.w, c);
            bool p = (d >= th);
            unsigned long long mk = __ballot(p);
            if (mk) {
                if (p) {
                    int pos = wcnt + (int)__popcll(mk & below);
                    if (pos < FCAP) bufi[wid][pos] = gi;
                }
                wcnt += (int)__popcll(mk);
            }
        }
    }
    // no block barrier needed: each wave reads only its own bufi row

    int mi_keep = 0;
    if (wcnt <= FCAP) {
        float sv[4]; int si[4];
#pragma unroll
        for (int r = 0; r < 4; ++r) {
            int j = r * 64 + lane;
            bool ok = j < wcnt;
            int sidx = ok ? bufi[wid][j] : 0;
            float dv = pair_dist4(qp.x, qp.y, qp.z, qp.w, pk[sidx]);
            sv[r] = ok ? dv : -INFINITY;
            si[r] = ok ? sidx : 0x7fffffff;
        }
        for (int r = 0; r < KNN; ++r) {
            float lv = -INFINITY; int li = 0x7fffffff; int ls = -1;
#pragma unroll
            for (int s3 = 0; s3 < 4; ++s3) {
                bool g = (sv[s3] > lv) || (sv[s3] == lv && si[s3] < li);
                if (g) { lv = sv[s3]; li = si[s3]; ls = s3; }
            }
            float wv = lv; int wi = li;
#pragma unroll
            for (int m = 32; m >= 1; m >>= 1) {
                float ov = __shfl_xor(wv, m); int oi = __shfl_xor(wi, m);
                if (ov > wv || (ov == wv && oi < wi)) { wv = ov; wi = oi; }
            }
            if (lv == wv && li == wi) {
#pragma unroll
                for (int s3 = 0; s3 < 4; ++s3)
                    if (s3 == ls) { sv[s3] = -INFINITY; si[s3] = 0x7fffffff; }
            }
            if (lane == 0) idx_out[q * KNN + r] = wi;
            if (lane == r) mi_keep = wi;
        }
    } else {
        // exact fallback: 20-round lex-max scan over all points (rare)
        float pv = INFINITY; int pi = -1;
        for (int r = 0; r < KNN; ++r) {
            float bv = -INFINITY; int bi = 0x7fffffff;
            for (int t = 0; t < NPTS / 64; ++t) {
                int i = t * 64 + lane;
                float d = pair_dist4(qp.x, qp.y, qp.z, qp.w, pk[i]);
                bool adm = (d < pv) || (d == pv && i > pi);
                if (adm && (d > bv || (d == bv && i < bi))) { bv = d; bi = i; }
            }
            float wv = bv; int wi = bi;
#pragma unroll
            for (int m = 32; m >= 1; m >>= 1) {
                float ov = __shfl_xor(wv, m); int oi = __shfl_xor(wi, m);
                if (ov > wv || (ov == wv && oi < wi)) { wv = ov; wi = oi; }
            }
            if (lane == 0) idx_out[q * KNN + r] = wi;
            if (lane == r) mi_keep = wi;
            pv = wv; pi = wi;
        }
    }
    // fused zsum for this query (o = lane)
    float An = P[q * 128 + lane];
    float Bn = P[q * 128 + 64 + lane];
    float base = Bn - An;
    float sum = 0.f, ss = 0.f;
#pragma unroll
    for (int kk = 0; kk < KNN; ++kk) {
        int m = __shfl(mi_keep, kk);
        float z = P[(size_t)m * 128 + lane] + base;
        sum += z;
        ss = fmaf(z, z, ss);
    }
    float* gg = gs + (blockIdx.x & (NREP - 1)) * 128;
    atomicAdd(gg + lane, sum);
    atomicAdd(gg + 64 + lane, ss);
}

// ---------------------------------------------------------------- z stats (stages 2,3)
__global__ __launch_bounds__(256) void zsum_kernel(const float* __restrict__ P,
                                                   const int* __restrict__ idx,
                                                   float* __restrict__ gs) {
    int tid = threadIdx.x;
    int o = tid & 63;
    float sum = 0.f, sumsq = 0.f;
    int n0 = blockIdx.x * 4;
#pragma unroll
    for (int ni = 0; ni < 4; ++ni) {
        int n = n0 + ni;
        float An = P[n * 128 + o];
        float Bn = P[n * 128 + 64 + o];
        float base = Bn - An;
#pragma unroll
        for (int kk2 = 0; kk2 < 5; ++kk2) {
            int kk = (tid >> 6) + kk2 * 4;
            int m = idx[n * KNN + kk];
            float z = P[m * 128 + o] + base;
            sum += z;
            sumsq = fmaf(z, z, sumsq);
        }
    }
    __shared__ float s1[256], s2[256];
    s1[tid] = sum; s2[tid] = sumsq;
    __syncthreads();
    if (tid < 64) {
        float a = s1[tid] + s1[tid + 64] + s1[tid + 128] + s1[tid + 192];
        float b = s2[tid] + s2[tid + 64] + s2[tid + 128] + s2[tid + 192];
        float* g = gs + (blockIdx.x & (NREP - 1)) * 128;
        atomicAdd(g + tid, a);
        atomicAdd(g + 64 + tid, b);
    }
}

// ---------------------------------------------------------------- conv GEMM: 80-row n-aligned tile
__global__ __launch_bounds__(256) void conv_gemm_kernel(const float* __restrict__ P,
                                                        const int* __restrict__ idx,
                                                        const float* __restrict__ gsIn,
                                                        const float* __restrict__ gIn,
                                                        const float* __restrict__ bIn,
                                                        const float* __restrict__ W,
                                                        float* __restrict__ gsOut,
                                                        float* __restrict__ Mx,
                                                        float* __restrict__ Mn) {
    __shared__ float As[80][68];
    __shared__ float Ws[64][68];
    __shared__ float saff[128];
    int tid = threadIdx.x;
    int r0 = blockIdx.x * 80;

    compute_affine(gsIn, gIn, bIn, saff, tid);
    for (int i2 = tid; i2 < 1024; i2 += 256) {
        int rr = i2 >> 4, c4 = (i2 & 15) * 4;
        *(float4*)&Ws[rr][c4] = *(const float4*)&W[rr * 64 + c4];
    }
    __syncthreads();

#pragma unroll 5
    for (int i2 = tid; i2 < 1280; i2 += 256) {
        int rr = i2 >> 4, c4 = (i2 & 15) * 4;
        int grow = r0 + rr;
        int n = grow / 20;
        int m = idx[grow];
        float4 zn = *(const float4*)&P[(size_t)m * 128 + c4];
        float4 an = *(const float4*)&P[(size_t)n * 128 + c4];
        float4 bn = *(const float4*)&P[(size_t)n * 128 + 64 + c4];
        float4 ov; float z;
        z = zn.x + (bn.x - an.x); ov.x = lrelu(fmaf(z, saff[c4 + 0], saff[64 + c4 + 0]));
        z = zn.y + (bn.y - an.y); ov.y = lrelu(fmaf(z, saff[c4 + 1], saff[64 + c4 + 1]));
        z = zn.z + (bn.z - an.z); ov.z = lrelu(fmaf(z, saff[c4 + 2], saff[64 + c4 + 2]));
        z = zn.w + (bn.w - an.w); ov.w = lrelu(fmaf(z, saff[c4 + 3], saff[64 + c4 + 3]));
        *(float4*)&As[rr][c4] = ov;
    }
    __syncthreads();

    int ty = tid >> 4, tx = tid & 15;
    float acc[5][4];
#pragma unroll
    for (int i = 0; i < 5; ++i)
#pragma unroll
        for (int j = 0; j < 4; ++j) acc[i][j] = 0.f;

    for (int c4 = 0; c4 < 64; c4 += 4) {
        float4 a4[5], w4[4];
#pragma unroll
        for (int i = 0; i < 5; ++i) a4[i] = *(const float4*)&As[ty + 16 * i][c4];
#pragma unroll
        for (int j = 0; j < 4; ++j) w4[j] = *(const float4*)&Ws[tx + 16 * j][c4];
#pragma unroll
        for (int i = 0; i < 5; ++i)
#pragma unroll
            for (int j = 0; j < 4; ++j) {
                acc[i][j] = fmaf(a4[i].x, w4[j].x, acc[i][j]);
                acc[i][j] = fmaf(a4[i].y, w4[j].y, acc[i][j]);
                acc[i][j] = fmaf(a4[i].z, w4[j].z, acc[i][j]);
                acc[i][j] = fmaf(a4[i].w, w4[j].w, acc[i][j]);
            }
    }
    __syncthreads();

#pragma unroll
    for (int i = 0; i < 5; ++i)
#pragma unroll
        for (int j = 0; j < 4; ++j) As[ty + 16 * i][tx + 16 * j] = acc[i][j];
    __syncthreads();

    int a = tid >> 6, o = tid & 63;
    float mxv = -INFINITY, mnv = INFINITY, s = 0.f, ss = 0.f;
#pragma unroll
    for (int r = 0; r < 20; ++r) {
        float v = As[20 * a + r][o];
        mxv = fmaxf(mxv, v); mnv = fminf(mnv, v);
        s += v; ss = fmaf(v, v, ss);
    }
    int n = blockIdx.x * 4 + a;
    Mx[n * 64 + o] = mxv;
    Mn[n * 64 + o] = mnv;
    float* sred = &Ws[0][0];
    float* ssred = sred + 256;
    sred[a * 64 + o] = s;
    ssred[a * 64 + o] = ss;
    __syncthreads();
    if (tid < 64) {
        float ts = sred[tid] + sred[64 + tid] + sred[128 + tid] + sred[192 + tid];
        float tss = ssred[tid] + ssred[64 + tid] + ssred[128 + tid] + ssred[192 + tid];
        float* gg = gsOut + (blockIdx.x & (NREP - 1)) * 128;
        atomicAdd(gg + tid, ts);
        atomicAdd(gg + 64 + tid, tss);
    }
}

// ---------------------------------------------------------------- pool + next-stage projection
__global__ __launch_bounds__(256) void pool_proj_kernel(const float* __restrict__ Mx,
                                                        const float* __restrict__ Mn,
                                                        const float* __restrict__ gsIn,
                                                        const float* __restrict__ g,
                                                        const float* __restrict__ b,
                                                        const float* __restrict__ Wt,
                                                        float* __restrict__ Xout,
                                                        float* __restrict__ Pout) {
    __shared__ float saff[128];
    __shared__ float xs[4][64];
    int tid = threadIdx.x;
    compute_affine(gsIn, g, b, saff, tid);
    __syncthreads();
    int n0 = blockIdx.x * 4;
    int pp = tid >> 6, o = tid & 63;
    float sc = saff[o], sh = saff[64 + o];
    float v = (sc >= 0.f) ? Mx[(n0 + pp) * 64 + o] : Mn[(n0 + pp) * 64 + o];
    float xv = lrelu(fmaf(v, sc, sh));
    Xout[(n0 + pp) * 64 + o] = xv;
    xs[pp][o] = xv;
    __syncthreads();
    int o2 = tid & 127, h = tid >> 7;
    int p0 = h * 2, p1 = h * 2 + 1;
    float a0 = 0.f, a1 = 0.f;
    for (int c = 0; c < 64; ++c) {
        float w = Wt[c * 128 + o2];
        a0 = fmaf(xs[p0][c], w, a0);
        a1 = fmaf(xs[p1][c], w, a1);
    }
    Pout[(n0 + p0) * 128 + o2] = a0;
    Pout[(n0 + p1) * 128 + o2] = a1;
}

// ---------------------------------------------------------------- stage-3 fused edge+pool
__global__ __launch_bounds__(256) void zpool_kernel(const float* __restrict__ P,
                                                    const int* __restrict__ idx,
                                                    const float* __restrict__ gsIn,
                                                    const float* __restrict__ g,
                                                    const float* __restrict__ b,
                                                    float* __restrict__ Xout) {
    __shared__ float saff[128];
    int tid = threadIdx.x;
    compute_affine(gsIn, g, b, saff, tid);
    __syncthreads();
    int gid = blockIdx.x * 256 + tid;
    int n = gid >> 6, o = gid & 63;
    float An = P[n * 128 + o];
    float Bn = P[n * 128 + 64 + o];
    float base = Bn - An;
    float mxz = -INFINITY, mnz = INFINITY;
#pragma unroll
    for (int kk = 0; kk < KNN; ++kk) {
        int m = idx[n * KNN + kk];
        float z = P[m * 128 + o] + base;
        mxz = fmaxf(mxz, z); mnz = fminf(mnz, z);
    }
    float sc = saff[o], sh = saff[64 + o];
    float v = (sc >= 0.f) ? mxz : mnz;
    Xout[gid] = lrelu(fmaf(v, sc, sh));
}

// ---------------------------------------------------------------- fused final MLP (R14 form)
__global__ __launch_bounds__(128) void mlp_kernel(const float* __restrict__ x1,
                                                  const float* __restrict__ x2,
                                                  const float* __restrict__ x3,
                                                  const float* __restrict__ W9at,
                                                  const float* __restrict__ b9a,
                                                  const float* __restrict__ W9bt,
                                                  const float* __restrict__ b9b,
                                                  float* __restrict__ out) {
    __shared__ float hs[8][128];
    int tid = threadIdx.x;
    int j = tid;
    int n0 = blockIdx.x * 8;
    float acc[8];
    float bj = b9a[j];
#pragma unroll
    for (int p = 0; p < 8; ++p) acc[p] = bj;
    for (int c = 0; c < 64; ++c) {
        float w = W9at[c * 128 + j];
#pragma unroll
        for (int p = 0; p < 8; ++p) acc[p] = fmaf(x1[(n0 + p) * 64 + c], w, acc[p]);
    }
    for (int c = 0; c < 64; ++c) {
        float w = W9at[(64 + c) * 128 + j];
#pragma unroll
        for (int p = 0; p < 8; ++p) acc[p] = fmaf(x2[(n0 + p) * 64 + c], w, acc[p]);
    }
    for (int c = 0; c < 64; ++c) {
        float w = W9at[(128 + c) * 128 + j];
#pragma unroll
        for (int p = 0; p < 8; ++p) acc[p] = fmaf(x3[(n0 + p) * 64 + c], w, acc[p]);
    }
#pragma unroll
    for (int p = 0; p < 8; ++p) hs[p][j] = fmaxf(acc[p], 0.f);
    __syncthreads();
    int p2 = tid >> 4, j2 = tid & 15;
    float a = b9b[j2];
    for (int c = 0; c < 128; ++c) a = fmaf(hs[p2][c], W9bt[c * 16 + j2], a);
    out[j2 * NPTS + n0 + p2] = a;
}

// ---------------------------------------------------------------- launch
extern "C" void kernel_launch(void* const* d_in, const int* in_sizes, int n_in,
                              void* d_out, int out_size, void* d_ws, size_t ws_size,
                              hipStream_t stream) {
    const float* x   = (const float*)d_in[0];
    const float* W1  = (const float*)d_in[2];
    const float* g1  = (const float*)d_in[3];
    const float* b1  = (const float*)d_in[4];
    const float* W2  = (const float*)d_in[5];
    const float* g2  = (const float*)d_in[6];
    const float* b2  = (const float*)d_in[7];
    const float* W3  = (const float*)d_in[8];
    const float* g3  = (const float*)d_in[9];
    const float* b3  = (const float*)d_in[10];
    const float* W4  = (const float*)d_in[11];
    const float* g4  = (const float*)d_in[12];
    const float* b4  = (const float*)d_in[13];
    const float* W5  = (const float*)d_in[14];
    const float* g5  = (const float*)d_in[15];
    const float* b5  = (const float*)d_in[16];
    const float* W9a = (const float*)d_in[17];
    const float* b9a = (const float*)d_in[18];
    const float* W9b = (const float*)d_in[19];
    const float* b9b = (const float*)d_in[20];
    float* out = (float*)d_out;

    char* ws = (char*)d_ws;
    int*    idx    = (int*)(ws + 0);                 // 655360
    float4* pk     = (float4*)(ws + 655360);         // 131072
    float*  P      = (float*)(ws + 786432);          // 4 MB
    float*  Mx     = (float*)(ws + 4980736);         // 2 MB
    float*  Mn     = (float*)(ws + 7077888);         // 2 MB
    float*  gsAll  = (float*)(ws + 9175040);         // 163840
    float*  x1b    = (float*)(ws + 9338880);         // 2 MB
    float*  x2b    = (float*)(ws + 11436032);        // 2 MB
    float*  x3b    = (float*)(ws + 13533184);        // 2 MB
    float*  Wt3    = (float*)(ws + 15664640);        // 32768
    float*  Wt5    = (float*)(ws + 15697408);        // 32768
    float*  W9at   = (float*)(ws + 15730176);        // 98304
    float*  W9bt   = (float*)(ws + 15828480);        // 8192
    (void)ws_size; (void)in_sizes; (void)n_in; (void)out_size;

    float* gs1 = gsAll;
    float* gs2 = gsAll + 1 * NREP * 128;
    float* gs3 = gsAll + 2 * NREP * 128;
    float* gs4 = gsAll + 3 * NREP * 128;
    float* gs5 = gsAll + 4 * NREP * 128;

    prep_proj_kernel<<<1384, 256, 0, stream>>>(x, W1, W3, W5, W9a, W9b, pk, Wt3, Wt5, W9at, W9bt, gsAll, P);
    knn_fsel<<<NPTS / 4, 256, 0, stream>>>(pk, idx, P, gs1);

    // stage 1
    conv_gemm_kernel<<<NPTS * KNN / 80, 256, 0, stream>>>(P, idx, gs1, g1, b1, W2, gs2, Mx, Mn);
    pool_proj_kernel<<<NPTS / 4, 256, 0, stream>>>(Mx, Mn, gs2, g2, b2, Wt3, x1b, P);

    // stage 2
    zsum_kernel<<<NPTS / 4, 256, 0, stream>>>(P, idx, gs3);
    conv_gemm_kernel<<<NPTS * KNN / 80, 256, 0, stream>>>(P, idx, gs3, g3, b3, W4, gs4, Mx, Mn);
    pool_proj_kernel<<<NPTS / 4, 256, 0, stream>>>(Mx, Mn, gs4, g4, b4, Wt5, x2b, P);

    // stage 3
    zsum_kernel<<<NPTS / 4, 256, 0, stream>>>(P, idx, gs5);
    zpool_kernel<<<NPTS * 64 / 256, 256, 0, stream>>>(P, idx, gs5, g5, b5, x3b);

    // final MLP
    mlp_kernel<<<NPTS / 8, 128, 0, stream>>>(x1b, x2b, x3b, W9at, b9a, W9bt, b9b, out);
}

// Round 22
// 215.809 us; speedup vs baseline: 1.1165x; 1.1165x over previous
//
#include <hip/hip_runtime.h>

#define NPTS 8192
#define KNN  20
#define NREP 64
#define THSUB 2048
#define FCAP 256

__device__ __forceinline__ float pair_dist4(float qx, float qy, float qz, float xxn, float4 c) {
    float dot = fmaf(qz, c.z, fmaf(qy, c.y, qx * c.x));
    return fmaf(2.f, dot, -xxn) - c.w;
}
__device__ __forceinline__ float self_sq(float dx, float dy, float dz) {
    return fmaf(dz, dz, fmaf(dy, dy, dx * dx));
}
__device__ __forceinline__ float lrelu(float v) { return (v >= 0.f) ? v : 0.2f * v; }

__device__ __forceinline__ void compute_affine(const float* __restrict__ gs,
                                               const float* __restrict__ g,
                                               const float* __restrict__ b,
                                               float* saff, int tid) {
    if (tid < 64) {
        float s = 0.f, ss = 0.f;
        for (int r = 0; r < NREP; ++r) { s += gs[r * 128 + tid]; ss += gs[r * 128 + 64 + tid]; }
        const float invM = 1.f / (float)(NPTS * KNN);
        float mean = s * invM;
        float var = ss * invM - mean * mean;
        float sc = g[tid] * rsqrtf(var + 1e-5f);
        saff[tid] = sc;
        saff[64 + tid] = b[tid] - mean * sc;
    }
}

// ---------------------------------------------------------------- prep (zeroes gsAll)
__global__ __launch_bounds__(256) void prep_kernel(const float* __restrict__ x,
                                                   const float* __restrict__ W1,
                                                   const float* __restrict__ W3,
                                                   const float* __restrict__ W5,
                                                   const float* __restrict__ W9a,
                                                   const float* __restrict__ W9b,
                                                   float4* __restrict__ pk,
                                                   float* __restrict__ Wt1,
                                                   float* __restrict__ Wt3,
                                                   float* __restrict__ Wt5,
                                                   float* __restrict__ W9at,
                                                   float* __restrict__ W9bt,
                                                   float* __restrict__ gsAll) {
    int gid = blockIdx.x * 256 + threadIdx.x;
    if (gid < NPTS) {
        float dx = x[64 * NPTS + gid], dy = x[65 * NPTS + gid], dz = x[66 * NPTS + gid];
        pk[gid] = make_float4(dx, dy, dz, self_sq(dx, dy, dz));
        return;
    }
    gid -= NPTS;
    if (gid < 67 * 128) {
        int c = gid >> 7, o = gid & 127;
        Wt1[gid] = (o < 64) ? W1[o * 134 + c] : W1[(o - 64) * 134 + 67 + c];
        return;
    }
    gid -= 67 * 128;
    if (gid < 64 * 128) {
        int c = gid >> 7, o = gid & 127;
        Wt3[gid] = (o < 64) ? W3[o * 128 + c] : W3[(o - 64) * 128 + 64 + c];
        return;
    }
    gid -= 64 * 128;
    if (gid < 64 * 128) {
        int c = gid >> 7, o = gid & 127;
        Wt5[gid] = (o < 64) ? W5[o * 128 + c] : W5[(o - 64) * 128 + 64 + c];
        return;
    }
    gid -= 64 * 128;
    if (gid < 192 * 128) {
        int c = gid >> 7, j = gid & 127;
        W9at[gid] = W9a[j * 192 + c];
        return;
    }
    gid -= 192 * 128;
    if (gid < 128 * 16) {
        int c = gid >> 4, j = gid & 15;
        W9bt[gid] = W9b[j * 128 + c];
        return;
    }
    gid -= 128 * 16;
    if (gid < 5 * NREP * 128) gsAll[gid] = 0.f;
}

// ---------------------------------------------------------------- kNN theta (2048-subset) + stage-1 proj
__global__ __launch_bounds__(256) void knn_theta_proj(const float4* __restrict__ pk,
                                                      float* __restrict__ theta,
                                                      const float* __restrict__ X,
                                                      const float* __restrict__ Wt1,
                                                      float* __restrict__ P) {
    __shared__ float4 cpt[THSUB];
    int tid = threadIdx.x;
    if (blockIdx.x >= 512) {
        int bb = blockIdx.x - 512;
        int o = tid & 127, h = tid >> 7;
        int n0 = bb * 8 + h * 4;
        float acc[4] = {0.f, 0.f, 0.f, 0.f};
        for (int c = 0; c < 67; ++c) {
            float w = Wt1[c * 128 + o];
#pragma unroll
            for (int i = 0; i < 4; ++i) acc[i] = fmaf(X[(n0 + i) + c * NPTS], w, acc[i]);
        }
#pragma unroll
        for (int i = 0; i < 4; ++i) P[(n0 + i) * 128 + o] = acc[i];
        return;
    }
    int wid = tid >> 6, lane = tid & 63;
    int qbase = blockIdx.x * 16 + wid * 4;
    for (int i = tid; i < THSUB; i += 256) cpt[i] = pk[i];
    float qx[4], qy[4], qz[4], xxn[4], mv[4];
#pragma unroll
    for (int qi = 0; qi < 4; ++qi) {
        float4 qp = pk[qbase + qi];
        qx[qi] = qp.x; qy[qi] = qp.y; qz[qi] = qp.z; xxn[qi] = qp.w;
        mv[qi] = -INFINITY;
    }
    __syncthreads();
    for (int t = 0; t < THSUB / 64; ++t) {
        float4 c = cpt[t * 64 + lane];
#pragma unroll
        for (int qi = 0; qi < 4; ++qi)
            mv[qi] = fmaxf(mv[qi], pair_dist4(qx[qi], qy[qi], qz[qi], xxn[qi], c));
    }
    // theta = 20th largest of 64 disjoint lane maxima over the subset => theta <= v20(full set)
#pragma unroll 1
    for (int qi = 0; qi < 4; ++qi) {
        float sel = mv[qi];
        float th = -INFINITY;
        for (int r = 0; r < KNN; ++r) {
            float v = sel;
#pragma unroll
            for (int m = 32; m >= 1; m >>= 1) v = fmaxf(v, __shfl_xor(v, m));
            th = v;
            unsigned long long bm = __ballot(sel == v);
            if (lane == __ffsll(bm) - 1) sel = -INFINITY;
        }
        if (lane == 0) theta[qbase + qi] = th - 1e-3f;
    }
}

// ---------------------------------------------------------------- fused filter + select + zsum1
// 4 queries/block, 1 query/wave; register-wcnt compaction; survivors in LDS.
__global__ __launch_bounds__(256) void knn_fsel(const float4* __restrict__ pk,
                                                const float* __restrict__ theta,
                                                int* __restrict__ idx_out,
                                                const float* __restrict__ P,
                                                float* __restrict__ gs) {
    __shared__ float4 cpt[1024];
    __shared__ int bufi[4][FCAP];
    int tid = threadIdx.x, wid = tid >> 6, lane = tid & 63;
    int q = blockIdx.x * 4 + wid;
    float4 qp = pk[q];
    float th = theta[q];
    int wcnt = 0;
    unsigned long long below = (1ull << lane) - 1ull;

    for (int ch = 0; ch < 8; ++ch) {
        __syncthreads();
        for (int i = tid; i < 1024; i += 256) cpt[i] = pk[ch * 1024 + i];
        __syncthreads();
        for (int t = 0; t < 16; ++t) {
            int gi = ch * 1024 + t * 64 + lane;
            float4 c = cpt[t * 64 + lane];
            float d = pair_dist4(qp.x, qp.y, qp.z, qp.w, c);
            bool p = (d >= th);
            unsigned long long mk = __ballot(p);
            if (p) {
                int pos = wcnt + (int)__popcll(mk & below);
                if (pos < FCAP) bufi[wid][pos] = gi;
            }
            wcnt += (int)__popcll(mk);
        }
    }
    // no block barrier needed: each wave reads only its own bufi row

    int mi_keep = 0;
    if (wcnt <= FCAP) {
        float sv[4]; int si[4];
#pragma unroll
        for (int r = 0; r < 4; ++r) {
            int j = r * 64 + lane;
            bool ok = j < wcnt;
            int sidx = ok ? bufi[wid][j] : 0;
            float dv = pair_dist4(qp.x, qp.y, qp.z, qp.w, pk[sidx]);
            sv[r] = ok ? dv : -INFINITY;
            si[r] = ok ? sidx : 0x7fffffff;
        }
        for (int r = 0; r < KNN; ++r) {
            float lv = -INFINITY; int li = 0x7fffffff; int ls = -1;
#pragma unroll
            for (int s3 = 0; s3 < 4; ++s3) {
                bool g = (sv[s3] > lv) || (sv[s3] == lv && si[s3] < li);
                if (g) { lv = sv[s3]; li = si[s3]; ls = s3; }
            }
            float wv = lv; int wi = li;
#pragma unroll
            for (int m = 32; m >= 1; m >>= 1) {
                float ov = __shfl_xor(wv, m); int oi = __shfl_xor(wi, m);
                if (ov > wv || (ov == wv && oi < wi)) { wv = ov; wi = oi; }
            }
            if (lv == wv && li == wi) {
#pragma unroll
                for (int s3 = 0; s3 < 4; ++s3)
                    if (s3 == ls) { sv[s3] = -INFINITY; si[s3] = 0x7fffffff; }
            }
            if (lane == 0) idx_out[q * KNN + r] = wi;
            if (lane == r) mi_keep = wi;
        }
    } else {
        // exact fallback: 20-round lex-max scan over all points (rare)
        float pv = INFINITY; int pi = -1;
        for (int r = 0; r < KNN; ++r) {
            float bv = -INFINITY; int bi = 0x7fffffff;
            for (int t = 0; t < NPTS / 64; ++t) {
                int i = t * 64 + lane;
                float d = pair_dist4(qp.x, qp.y, qp.z, qp.w, pk[i]);
                bool adm = (d < pv) || (d == pv && i > pi);
                if (adm && (d > bv || (d == bv && i < bi))) { bv = d; bi = i; }
            }
            float wv = bv; int wi = bi;
#pragma unroll
            for (int m = 32; m >= 1; m >>= 1) {
                float ov = __shfl_xor(wv, m); int oi = __shfl_xor(wi, m);
                if (ov > wv || (ov == wv && oi < wi)) { wv = ov; wi = oi; }
            }
            if (lane == 0) idx_out[q * KNN + r] = wi;
            if (lane == r) mi_keep = wi;
            pv = wv; pi = wi;
        }
    }
    // fused zsum for this query (o = lane)
    float An = P[q * 128 + lane];
    float Bn = P[q * 128 + 64 + lane];
    float base = Bn - An;
    float sum = 0.f, ss = 0.f;
#pragma unroll
    for (int kk = 0; kk < KNN; ++kk) {
        int m = __shfl(mi_keep, kk);
        float z = P[(size_t)m * 128 + lane] + base;
        sum += z;
        ss = fmaf(z, z, ss);
    }
    float* gg = gs + (blockIdx.x & (NREP - 1)) * 128;
    atomicAdd(gg + lane, sum);
    atomicAdd(gg + 64 + lane, ss);
}

// ---------------------------------------------------------------- z stats (stages 2,3)
__global__ __launch_bounds__(256) void zsum_kernel(const float* __restrict__ P,
                                                   const int* __restrict__ idx,
                                                   float* __restrict__ gs) {
    int tid = threadIdx.x;
    int o = tid & 63;
    float sum = 0.f, sumsq = 0.f;
    int n0 = blockIdx.x * 4;
#pragma unroll
    for (int ni = 0; ni < 4; ++ni) {
        int n = n0 + ni;
        float An = P[n * 128 + o];
        float Bn = P[n * 128 + 64 + o];
        float base = Bn - An;
#pragma unroll
        for (int kk2 = 0; kk2 < 5; ++kk2) {
            int kk = (tid >> 6) + kk2 * 4;
            int m = idx[n * KNN + kk];
            float z = P[m * 128 + o] + base;
            sum += z;
            sumsq = fmaf(z, z, sumsq);
        }
    }
    __shared__ float s1[256], s2[256];
    s1[tid] = sum; s2[tid] = sumsq;
    __syncthreads();
    if (tid < 64) {
        float a = s1[tid] + s1[tid + 64] + s1[tid + 128] + s1[tid + 192];
        float b = s2[tid] + s2[tid + 64] + s2[tid + 128] + s2[tid + 192];
        float* g = gs + (blockIdx.x & (NREP - 1)) * 128;
        atomicAdd(g + tid, a);
        atomicAdd(g + 64 + tid, b);
    }
}

// ---------------------------------------------------------------- conv GEMM: 80-row n-aligned tile
__global__ __launch_bounds__(256) void conv_gemm_kernel(const float* __restrict__ P,
                                                        const int* __restrict__ idx,
                                                        const float* __restrict__ gsIn,
                                                        const float* __restrict__ gIn,
                                                        const float* __restrict__ bIn,
                                                        const float* __restrict__ W,
                                                        float* __restrict__ gsOut,
                                                        float* __restrict__ Mx,
                                                        float* __restrict__ Mn) {
    __shared__ float As[80][68];
    __shared__ float Ws[64][68];
    __shared__ float saff[128];
    int tid = threadIdx.x;
    int r0 = blockIdx.x * 80;

    compute_affine(gsIn, gIn, bIn, saff, tid);
    for (int i2 = tid; i2 < 1024; i2 += 256) {
        int rr = i2 >> 4, c4 = (i2 & 15) * 4;
        *(float4*)&Ws[rr][c4] = *(const float4*)&W[rr * 64 + c4];
    }
    __syncthreads();

#pragma unroll 5
    for (int i2 = tid; i2 < 1280; i2 += 256) {
        int rr = i2 >> 4, c4 = (i2 & 15) * 4;
        int grow = r0 + rr;
        int n = grow / 20;
        int m = idx[grow];
        float4 zn = *(const float4*)&P[(size_t)m * 128 + c4];
        float4 an = *(const float4*)&P[(size_t)n * 128 + c4];
        float4 bn = *(const float4*)&P[(size_t)n * 128 + 64 + c4];
        float4 ov; float z;
        z = zn.x + (bn.x - an.x); ov.x = lrelu(fmaf(z, saff[c4 + 0], saff[64 + c4 + 0]));
        z = zn.y + (bn.y - an.y); ov.y = lrelu(fmaf(z, saff[c4 + 1], saff[64 + c4 + 1]));
        z = zn.z + (bn.z - an.z); ov.z = lrelu(fmaf(z, saff[c4 + 2], saff[64 + c4 + 2]));
        z = zn.w + (bn.w - an.w); ov.w = lrelu(fmaf(z, saff[c4 + 3], saff[64 + c4 + 3]));
        *(float4*)&As[rr][c4] = ov;
    }
    __syncthreads();

    int ty = tid >> 4, tx = tid & 15;
    float acc[5][4];
#pragma unroll
    for (int i = 0; i < 5; ++i)
#pragma unroll
        for (int j = 0; j < 4; ++j) acc[i][j] = 0.f;

    for (int c4 = 0; c4 < 64; c4 += 4) {
        float4 a4[5], w4[4];
#pragma unroll
        for (int i = 0; i < 5; ++i) a4[i] = *(const float4*)&As[ty + 16 * i][c4];
#pragma unroll
        for (int j = 0; j < 4; ++j) w4[j] = *(const float4*)&Ws[tx + 16 * j][c4];
#pragma unroll
        for (int i = 0; i < 5; ++i)
#pragma unroll
            for (int j = 0; j < 4; ++j) {
                acc[i][j] = fmaf(a4[i].x, w4[j].x, acc[i][j]);
                acc[i][j] = fmaf(a4[i].y, w4[j].y, acc[i][j]);
                acc[i][j] = fmaf(a4[i].z, w4[j].z, acc[i][j]);
                acc[i][j] = fmaf(a4[i].w, w4[j].w, acc[i][j]);
            }
    }
    __syncthreads();

#pragma unroll
    for (int i = 0; i < 5; ++i)
#pragma unroll
        for (int j = 0; j < 4; ++j) As[ty + 16 * i][tx + 16 * j] = acc[i][j];
    __syncthreads();

    int a = tid >> 6, o = tid & 63;
    float mxv = -INFINITY, mnv = INFINITY, s = 0.f, ss = 0.f;
#pragma unroll
    for (int r = 0; r < 20; ++r) {
        float v = As[20 * a + r][o];
        mxv = fmaxf(mxv, v); mnv = fminf(mnv, v);
        s += v; ss = fmaf(v, v, ss);
    }
    int n = blockIdx.x * 4 + a;
    Mx[n * 64 + o] = mxv;
    Mn[n * 64 + o] = mnv;
    float* sred = &Ws[0][0];
    float* ssred = sred + 256;
    sred[a * 64 + o] = s;
    ssred[a * 64 + o] = ss;
    __syncthreads();
    if (tid < 64) {
        float ts = sred[tid] + sred[64 + tid] + sred[128 + tid] + sred[192 + tid];
        float tss = ssred[tid] + ssred[64 + tid] + ssred[128 + tid] + ssred[192 + tid];
        float* gg = gsOut + (blockIdx.x & (NREP - 1)) * 128;
        atomicAdd(gg + tid, ts);
        atomicAdd(gg + 64 + tid, tss);
    }
}

// ---------------------------------------------------------------- pool + next-stage projection
__global__ __launch_bounds__(256) void pool_proj_kernel(const float* __restrict__ Mx,
                                                        const float* __restrict__ Mn,
                                                        const float* __restrict__ gsIn,
                                                        const float* __restrict__ g,
                                                        const float* __restrict__ b,
                                                        const float* __restrict__ Wt,
                                                        float* __restrict__ Xout,
                                                        float* __restrict__ Pout) {
    __shared__ float saff[128];
    __shared__ float xs[4][64];
    int tid = threadIdx.x;
    compute_affine(gsIn, g, b, saff, tid);
    __syncthreads();
    int n0 = blockIdx.x * 4;
    int pp = tid >> 6, o = tid & 63;
    float sc = saff[o], sh = saff[64 + o];
    float v = (sc >= 0.f) ? Mx[(n0 + pp) * 64 + o] : Mn[(n0 + pp) * 64 + o];
    float xv = lrelu(fmaf(v, sc, sh));
    Xout[(n0 + pp) * 64 + o] = xv;
    xs[pp][o] = xv;
    __syncthreads();
    int o2 = tid & 127, h = tid >> 7;
    int p0 = h * 2, p1 = h * 2 + 1;
    float a0 = 0.f, a1 = 0.f;
    for (int c = 0; c < 64; ++c) {
        float w = Wt[c * 128 + o2];
        a0 = fmaf(xs[p0][c], w, a0);
        a1 = fmaf(xs[p1][c], w, a1);
    }
    Pout[(n0 + p0) * 128 + o2] = a0;
    Pout[(n0 + p1) * 128 + o2] = a1;
}

// ---------------------------------------------------------------- fused final MLP (+ inline stage-3 edge+pool)
__global__ __launch_bounds__(128) void mlp_kernel(const float* __restrict__ x1,
                                                  const float* __restrict__ x2,
                                                  const float* __restrict__ P,
                                                  const int* __restrict__ idx,
                                                  const float* __restrict__ gs5,
                                                  const float* __restrict__ g5,
                                                  const float* __restrict__ b5,
                                                  const float* __restrict__ W9at,
                                                  const float* __restrict__ b9a,
                                                  const float* __restrict__ W9bt,
                                                  const float* __restrict__ b9b,
                                                  float* __restrict__ out) {
    __shared__ float saff[128];
    __shared__ float xs3[8][64];
    __shared__ float hs[8][128];
    int tid = threadIdx.x;
    compute_affine(gs5, g5, b5, saff, tid);
    __syncthreads();
    int n0 = blockIdx.x * 8;
    // inline zpool: compute x3 for this block's 8 points (2 waves x 4 points each)
    {
        int o = tid & 63;
        for (int pp = (tid >> 6); pp < 8; pp += 2) {
            int n = n0 + pp;
            float An = P[n * 128 + o];
            float Bn = P[n * 128 + 64 + o];
            float base = Bn - An;
            float mxz = -INFINITY, mnz = INFINITY;
#pragma unroll
            for (int kk = 0; kk < KNN; ++kk) {
                int m = idx[n * KNN + kk];
                float z = P[(size_t)m * 128 + o] + base;
                mxz = fmaxf(mxz, z); mnz = fminf(mnz, z);
            }
            float sc = saff[o], sh = saff[64 + o];
            float v = (sc >= 0.f) ? mxz : mnz;
            xs3[pp][o] = lrelu(fmaf(v, sc, sh));
        }
    }
    __syncthreads();

    int j = tid;
    float acc[8];
    float bj = b9a[j];
#pragma unroll
    for (int p = 0; p < 8; ++p) acc[p] = bj;
    for (int c = 0; c < 64; ++c) {
        float w = W9at[c * 128 + j];
#pragma unroll
        for (int p = 0; p < 8; ++p) acc[p] = fmaf(x1[(n0 + p) * 64 + c], w, acc[p]);
    }
    for (int c = 0; c < 64; ++c) {
        float w = W9at[(64 + c) * 128 + j];
#pragma unroll
        for (int p = 0; p < 8; ++p) acc[p] = fmaf(x2[(n0 + p) * 64 + c], w, acc[p]);
    }
    for (int c = 0; c < 64; ++c) {
        float w = W9at[(128 + c) * 128 + j];
#pragma unroll
        for (int p = 0; p < 8; ++p) acc[p] = fmaf(xs3[p][c], w, acc[p]);
    }
#pragma unroll
    for (int p = 0; p < 8; ++p) hs[p][j] = fmaxf(acc[p], 0.f);
    __syncthreads();
    int p2 = tid >> 4, j2 = tid & 15;
    float a = b9b[j2];
    for (int c = 0; c < 128; ++c) a = fmaf(hs[p2][c], W9bt[c * 16 + j2], a);
    out[j2 * NPTS + n0 + p2] = a;
}

// ---------------------------------------------------------------- launch
extern "C" void kernel_launch(void* const* d_in, const int* in_sizes, int n_in,
                              void* d_out, int out_size, void* d_ws, size_t ws_size,
                              hipStream_t stream) {
    const float* x   = (const float*)d_in[0];
    const float* W1  = (const float*)d_in[2];
    const float* g1  = (const float*)d_in[3];
    const float* b1  = (const float*)d_in[4];
    const float* W2  = (const float*)d_in[5];
    const float* g2  = (const float*)d_in[6];
    const float* b2  = (const float*)d_in[7];
    const float* W3  = (const float*)d_in[8];
    const float* g3  = (const float*)d_in[9];
    const float* b3  = (const float*)d_in[10];
    const float* W4  = (const float*)d_in[11];
    const float* g4  = (const float*)d_in[12];
    const float* b4  = (const float*)d_in[13];
    const float* W5  = (const float*)d_in[14];
    const float* g5  = (const float*)d_in[15];
    const float* b5  = (const float*)d_in[16];
    const float* W9a = (const float*)d_in[17];
    const float* b9a = (const float*)d_in[18];
    const float* W9b = (const float*)d_in[19];
    const float* b9b = (const float*)d_in[20];
    float* out = (float*)d_out;

    char* ws = (char*)d_ws;
    int*    idx    = (int*)(ws + 0);                 // 655360
    float4* pk     = (float4*)(ws + 655360);         // 131072
    float*  P      = (float*)(ws + 786432);          // 4 MB
    float*  Mx     = (float*)(ws + 4980736);         // 2 MB
    float*  Mn     = (float*)(ws + 7077888);         // 2 MB
    float*  gsAll  = (float*)(ws + 9175040);         // 163840
    float*  x1b    = (float*)(ws + 9338880);         // 2 MB
    float*  x2b    = (float*)(ws + 11436032);        // 2 MB
    float*  Wt1    = (float*)(ws + 15630336);        // 34304
    float*  Wt3    = (float*)(ws + 15664640);        // 32768
    float*  Wt5    = (float*)(ws + 15697408);        // 32768
    float*  W9at   = (float*)(ws + 15730176);        // 98304
    float*  W9bt   = (float*)(ws + 15828480);        // 8192
    float*  theta  = (float*)(ws + 15836672);        // 32768
    (void)ws_size; (void)in_sizes; (void)n_in; (void)out_size;

    float* gs1 = gsAll;
    float* gs2 = gsAll + 1 * NREP * 128;
    float* gs3 = gsAll + 2 * NREP * 128;
    float* gs4 = gsAll + 3 * NREP * 128;
    float* gs5 = gsAll + 4 * NREP * 128;

    prep_kernel<<<394, 256, 0, stream>>>(x, W1, W3, W5, W9a, W9b, pk, Wt1, Wt3, Wt5, W9at, W9bt, gsAll);
    knn_theta_proj<<<1536, 256, 0, stream>>>(pk, theta, x, Wt1, P);
    knn_fsel<<<NPTS / 4, 256, 0, stream>>>(pk, theta, idx, P, gs1);

    // stage 1
    conv_gemm_kernel<<<NPTS * KNN / 80, 256, 0, stream>>>(P, idx, gs1, g1, b1, W2, gs2, Mx, Mn);
    pool_proj_kernel<<<NPTS / 4, 256, 0, stream>>>(Mx, Mn, gs2, g2, b2, Wt3, x1b, P);

    // stage 2
    zsum_kernel<<<NPTS / 4, 256, 0, stream>>>(P, idx, gs3);
    conv_gemm_kernel<<<NPTS * KNN / 80, 256, 0, stream>>>(P, idx, gs3, g3, b3, W4, gs4, Mx, Mn);
    pool_proj_kernel<<<NPTS / 4, 256, 0, stream>>>(Mx, Mn, gs4, g4, b4, Wt5, x2b, P);

    // stage 3: zsum for BN stats, then mlp computes edge+pool inline
    zsum_kernel<<<NPTS / 4, 256, 0, stream>>>(P, idx, gs5);
    mlp_kernel<<<NPTS / 8, 128, 0, stream>>>(x1b, x2b, P, idx, gs5, g5, b5, W9at, b9a, W9bt, b9b, out);
}

// Round 23
// 211.551 us; speedup vs baseline: 1.1390x; 1.0201x over previous
//
#include <hip/hip_runtime.h>

#define NPTS 8192
#define KNN  20
#define NREP 64
#define THSUB 2048
#define FCAP 256

__device__ __forceinline__ float pair_dist4(float qx, float qy, float qz, float xxn, float4 c) {
    float dot = fmaf(qz, c.z, fmaf(qy, c.y, qx * c.x));
    return fmaf(2.f, dot, -xxn) - c.w;
}
__device__ __forceinline__ float self_sq(float dx, float dy, float dz) {
    return fmaf(dz, dz, fmaf(dy, dy, dx * dx));
}
__device__ __forceinline__ float lrelu(float v) { return (v >= 0.f) ? v : 0.2f * v; }

__device__ __forceinline__ void compute_affine(const float* __restrict__ gs,
                                               const float* __restrict__ g,
                                               const float* __restrict__ b,
                                               float* saff, int tid) {
    if (tid < 64) {
        float s = 0.f, ss = 0.f;
        for (int r = 0; r < NREP; ++r) { s += gs[r * 128 + tid]; ss += gs[r * 128 + 64 + tid]; }
        const float invM = 1.f / (float)(NPTS * KNN);
        float mean = s * invM;
        float var = ss * invM - mean * mean;
        float sc = g[tid] * rsqrtf(var + 1e-5f);
        saff[tid] = sc;
        saff[64 + tid] = b[tid] - mean * sc;
    }
}

// ---------------------------------------------------------------- prep (zeroes gsAll)
__global__ __launch_bounds__(256) void prep_kernel(const float* __restrict__ x,
                                                   const float* __restrict__ W1,
                                                   const float* __restrict__ W3,
                                                   const float* __restrict__ W5,
                                                   const float* __restrict__ W9a,
                                                   const float* __restrict__ W9b,
                                                   float4* __restrict__ pk,
                                                   float* __restrict__ Wt1,
                                                   float* __restrict__ Wt3,
                                                   float* __restrict__ Wt5,
                                                   float* __restrict__ W9at,
                                                   float* __restrict__ W9bt,
                                                   float* __restrict__ gsAll) {
    int gid = blockIdx.x * 256 + threadIdx.x;
    if (gid < NPTS) {
        float dx = x[64 * NPTS + gid], dy = x[65 * NPTS + gid], dz = x[66 * NPTS + gid];
        pk[gid] = make_float4(dx, dy, dz, self_sq(dx, dy, dz));
        return;
    }
    gid -= NPTS;
    if (gid < 67 * 128) {
        int c = gid >> 7, o = gid & 127;
        Wt1[gid] = (o < 64) ? W1[o * 134 + c] : W1[(o - 64) * 134 + 67 + c];
        return;
    }
    gid -= 67 * 128;
    if (gid < 64 * 128) {
        int c = gid >> 7, o = gid & 127;
        Wt3[gid] = (o < 64) ? W3[o * 128 + c] : W3[(o - 64) * 128 + 64 + c];
        return;
    }
    gid -= 64 * 128;
    if (gid < 64 * 128) {
        int c = gid >> 7, o = gid & 127;
        Wt5[gid] = (o < 64) ? W5[o * 128 + c] : W5[(o - 64) * 128 + 64 + c];
        return;
    }
    gid -= 64 * 128;
    if (gid < 192 * 128) {
        int c = gid >> 7, j = gid & 127;
        W9at[gid] = W9a[j * 192 + c];
        return;
    }
    gid -= 192 * 128;
    if (gid < 128 * 16) {
        int c = gid >> 4, j = gid & 15;
        W9bt[gid] = W9b[j * 128 + c];
        return;
    }
    gid -= 128 * 16;
    if (gid < 5 * NREP * 128) gsAll[gid] = 0.f;
}

// ---------------------------------------------------------------- kNN theta (2048-subset) + stage-1 proj
__global__ __launch_bounds__(256) void knn_theta_proj(const float4* __restrict__ pk,
                                                      float* __restrict__ theta,
                                                      const float* __restrict__ X,
                                                      const float* __restrict__ Wt1,
                                                      float* __restrict__ P) {
    __shared__ float4 cpt[THSUB];
    int tid = threadIdx.x;
    if (blockIdx.x >= 512) {
        int bb = blockIdx.x - 512;
        int o = tid & 127, h = tid >> 7;
        int n0 = bb * 8 + h * 4;
        float acc[4] = {0.f, 0.f, 0.f, 0.f};
        for (int c = 0; c < 67; ++c) {
            float w = Wt1[c * 128 + o];
#pragma unroll
            for (int i = 0; i < 4; ++i) acc[i] = fmaf(X[(n0 + i) + c * NPTS], w, acc[i]);
        }
#pragma unroll
        for (int i = 0; i < 4; ++i) P[(n0 + i) * 128 + o] = acc[i];
        return;
    }
    int wid = tid >> 6, lane = tid & 63;
    int qbase = blockIdx.x * 16 + wid * 4;
    for (int i = tid; i < THSUB; i += 256) cpt[i] = pk[i];
    float qx[4], qy[4], qz[4], xxn[4], mv[4];
#pragma unroll
    for (int qi = 0; qi < 4; ++qi) {
        float4 qp = pk[qbase + qi];
        qx[qi] = qp.x; qy[qi] = qp.y; qz[qi] = qp.z; xxn[qi] = qp.w;
        mv[qi] = -INFINITY;
    }
    __syncthreads();
    for (int t = 0; t < THSUB / 64; ++t) {
        float4 c = cpt[t * 64 + lane];
#pragma unroll
        for (int qi = 0; qi < 4; ++qi)
            mv[qi] = fmaxf(mv[qi], pair_dist4(qx[qi], qy[qi], qz[qi], xxn[qi], c));
    }
    // theta = 20th largest of 64 disjoint lane maxima over the subset => theta <= v20(full set)
#pragma unroll 1
    for (int qi = 0; qi < 4; ++qi) {
        float sel = mv[qi];
        float th = -INFINITY;
        for (int r = 0; r < KNN; ++r) {
            float v = sel;
#pragma unroll
            for (int m = 32; m >= 1; m >>= 1) v = fmaxf(v, __shfl_xor(v, m));
            th = v;
            unsigned long long bm = __ballot(sel == v);
            if (lane == __ffsll(bm) - 1) sel = -INFINITY;
        }
        if (lane == 0) theta[qbase + qi] = th - 1e-3f;
    }
}

// ---------------------------------------------------------------- fused filter + select + zsum1
// 8 queries/block (512 thr, 8 waves), 1 query/wave; register-wcnt compaction; survivors in LDS.
__global__ __launch_bounds__(512) void knn_fsel(const float4* __restrict__ pk,
                                                const float* __restrict__ theta,
                                                int* __restrict__ idx_out,
                                                const float* __restrict__ P,
                                                float* __restrict__ gs) {
    __shared__ float4 cpt[1024];
    __shared__ int bufi[8][FCAP];
    int tid = threadIdx.x, wid = tid >> 6, lane = tid & 63;
    int q = blockIdx.x * 8 + wid;
    float4 qp = pk[q];
    float th = theta[q];
    int wcnt = 0;
    unsigned long long below = (1ull << lane) - 1ull;

    for (int ch = 0; ch < 8; ++ch) {
        __syncthreads();
        for (int i = tid; i < 1024; i += 512) cpt[i] = pk[ch * 1024 + i];
        __syncthreads();
        for (int t = 0; t < 16; ++t) {
            int gi = ch * 1024 + t * 64 + lane;
            float4 c = cpt[t * 64 + lane];
            float d = pair_dist4(qp.x, qp.y, qp.z, qp.w, c);
            bool p = (d >= th);
            unsigned long long mk = __ballot(p);
            if (p) {
                int pos = wcnt + (int)__popcll(mk & below);
                if (pos < FCAP) bufi[wid][pos] = gi;
            }
            wcnt += (int)__popcll(mk);
        }
    }
    // no block barrier needed: each wave reads only its own bufi row

    int mi_keep = 0;
    if (wcnt <= FCAP) {
        float sv[4]; int si[4];
#pragma unroll
        for (int r = 0; r < 4; ++r) {
            int j = r * 64 + lane;
            bool ok = j < wcnt;
            int sidx = ok ? bufi[wid][j] : 0;
            float dv = pair_dist4(qp.x, qp.y, qp.z, qp.w, pk[sidx]);
            sv[r] = ok ? dv : -INFINITY;
            si[r] = ok ? sidx : 0x7fffffff;
        }
        for (int r = 0; r < KNN; ++r) {
            float lv = -INFINITY; int li = 0x7fffffff; int ls = -1;
#pragma unroll
            for (int s3 = 0; s3 < 4; ++s3) {
                bool g = (sv[s3] > lv) || (sv[s3] == lv && si[s3] < li);
                if (g) { lv = sv[s3]; li = si[s3]; ls = s3; }
            }
            float wv = lv; int wi = li;
#pragma unroll
            for (int m = 32; m >= 1; m >>= 1) {
                float ov = __shfl_xor(wv, m); int oi = __shfl_xor(wi, m);
                if (ov > wv || (ov == wv && oi < wi)) { wv = ov; wi = oi; }
            }
            if (lv == wv && li == wi) {
#pragma unroll
                for (int s3 = 0; s3 < 4; ++s3)
                    if (s3 == ls) { sv[s3] = -INFINITY; si[s3] = 0x7fffffff; }
            }
            if (lane == 0) idx_out[q * KNN + r] = wi;
            if (lane == r) mi_keep = wi;
        }
    } else {
        // exact fallback: 20-round lex-max scan over all points (rare)
        float pv = INFINITY; int pi = -1;
        for (int r = 0; r < KNN; ++r) {
            float bv = -INFINITY; int bi = 0x7fffffff;
            for (int t = 0; t < NPTS / 64; ++t) {
                int i = t * 64 + lane;
                float d = pair_dist4(qp.x, qp.y, qp.z, qp.w, pk[i]);
                bool adm = (d < pv) || (d == pv && i > pi);
                if (adm && (d > bv || (d == bv && i < bi))) { bv = d; bi = i; }
            }
            float wv = bv; int wi = bi;
#pragma unroll
            for (int m = 32; m >= 1; m >>= 1) {
                float ov = __shfl_xor(wv, m); int oi = __shfl_xor(wi, m);
                if (ov > wv || (ov == wv && oi < wi)) { wv = ov; wi = oi; }
            }
            if (lane == 0) idx_out[q * KNN + r] = wi;
            if (lane == r) mi_keep = wi;
            pv = wv; pi = wi;
        }
    }
    // fused zsum for this query (o = lane)
    float An = P[q * 128 + lane];
    float Bn = P[q * 128 + 64 + lane];
    float base = Bn - An;
    float sum = 0.f, ss = 0.f;
#pragma unroll
    for (int kk = 0; kk < KNN; ++kk) {
        int m = __shfl(mi_keep, kk);
        float z = P[(size_t)m * 128 + lane] + base;
        sum += z;
        ss = fmaf(z, z, ss);
    }
    float* gg = gs + (blockIdx.x & (NREP - 1)) * 128;
    atomicAdd(gg + lane, sum);
    atomicAdd(gg + 64 + lane, ss);
}

// ---------------------------------------------------------------- z stats (stages 2,3)
__global__ __launch_bounds__(256) void zsum_kernel(const float* __restrict__ P,
                                                   const int* __restrict__ idx,
                                                   float* __restrict__ gs) {
    int tid = threadIdx.x;
    int o = tid & 63;
    float sum = 0.f, sumsq = 0.f;
    int n0 = blockIdx.x * 4;
#pragma unroll
    for (int ni = 0; ni < 4; ++ni) {
        int n = n0 + ni;
        float An = P[n * 128 + o];
        float Bn = P[n * 128 + 64 + o];
        float base = Bn - An;
#pragma unroll
        for (int kk2 = 0; kk2 < 5; ++kk2) {
            int kk = (tid >> 6) + kk2 * 4;
            int m = idx[n * KNN + kk];
            float z = P[m * 128 + o] + base;
            sum += z;
            sumsq = fmaf(z, z, sumsq);
        }
    }
    __shared__ float s1[256], s2[256];
    s1[tid] = sum; s2[tid] = sumsq;
    __syncthreads();
    if (tid < 64) {
        float a = s1[tid] + s1[tid + 64] + s1[tid + 128] + s1[tid + 192];
        float b = s2[tid] + s2[tid + 64] + s2[tid + 128] + s2[tid + 192];
        float* g = gs + (blockIdx.x & (NREP - 1)) * 128;
        atomicAdd(g + tid, a);
        atomicAdd(g + 64 + tid, b);
    }
}

// ---------------------------------------------------------------- conv GEMM: 80-row n-aligned tile
__global__ __launch_bounds__(256) void conv_gemm_kernel(const float* __restrict__ P,
                                                        const int* __restrict__ idx,
                                                        const float* __restrict__ gsIn,
                                                        const float* __restrict__ gIn,
                                                        const float* __restrict__ bIn,
                                                        const float* __restrict__ W,
                                                        float* __restrict__ gsOut,
                                                        float* __restrict__ Mx,
                                                        float* __restrict__ Mn) {
    __shared__ float As[80][68];
    __shared__ float Ws[64][68];
    __shared__ float saff[128];
    int tid = threadIdx.x;
    int r0 = blockIdx.x * 80;

    compute_affine(gsIn, gIn, bIn, saff, tid);
    for (int i2 = tid; i2 < 1024; i2 += 256) {
        int rr = i2 >> 4, c4 = (i2 & 15) * 4;
        *(float4*)&Ws[rr][c4] = *(const float4*)&W[rr * 64 + c4];
    }
    __syncthreads();

#pragma unroll 5
    for (int i2 = tid; i2 < 1280; i2 += 256) {
        int rr = i2 >> 4, c4 = (i2 & 15) * 4;
        int grow = r0 + rr;
        int n = grow / 20;
        int m = idx[grow];
        float4 zn = *(const float4*)&P[(size_t)m * 128 + c4];
        float4 an = *(const float4*)&P[(size_t)n * 128 + c4];
        float4 bn = *(const float4*)&P[(size_t)n * 128 + 64 + c4];
        float4 ov; float z;
        z = zn.x + (bn.x - an.x); ov.x = lrelu(fmaf(z, saff[c4 + 0], saff[64 + c4 + 0]));
        z = zn.y + (bn.y - an.y); ov.y = lrelu(fmaf(z, saff[c4 + 1], saff[64 + c4 + 1]));
        z = zn.z + (bn.z - an.z); ov.z = lrelu(fmaf(z, saff[c4 + 2], saff[64 + c4 + 2]));
        z = zn.w + (bn.w - an.w); ov.w = lrelu(fmaf(z, saff[c4 + 3], saff[64 + c4 + 3]));
        *(float4*)&As[rr][c4] = ov;
    }
    __syncthreads();

    int ty = tid >> 4, tx = tid & 15;
    float acc[5][4];
#pragma unroll
    for (int i = 0; i < 5; ++i)
#pragma unroll
        for (int j = 0; j < 4; ++j) acc[i][j] = 0.f;

    for (int c4 = 0; c4 < 64; c4 += 4) {
        float4 a4[5], w4[4];
#pragma unroll
        for (int i = 0; i < 5; ++i) a4[i] = *(const float4*)&As[ty + 16 * i][c4];
#pragma unroll
        for (int j = 0; j < 4; ++j) w4[j] = *(const float4*)&Ws[tx + 16 * j][c4];
#pragma unroll
        for (int i = 0; i < 5; ++i)
#pragma unroll
            for (int j = 0; j < 4; ++j) {
                acc[i][j] = fmaf(a4[i].x, w4[j].x, acc[i][j]);
                acc[i][j] = fmaf(a4[i].y, w4[j].y, acc[i][j]);
                acc[i][j] = fmaf(a4[i].z, w4[j].z, acc[i][j]);
                acc[i][j] = fmaf(a4[i].w, w4[j].w, acc[i][j]);
            }
    }
    __syncthreads();

#pragma unroll
    for (int i = 0; i < 5; ++i)
#pragma unroll
        for (int j = 0; j < 4; ++j) As[ty + 16 * i][tx + 16 * j] = acc[i][j];
    __syncthreads();

    int a = tid >> 6, o = tid & 63;
    float mxv = -INFINITY, mnv = INFINITY, s = 0.f, ss = 0.f;
#pragma unroll
    for (int r = 0; r < 20; ++r) {
        float v = As[20 * a + r][o];
        mxv = fmaxf(mxv, v); mnv = fminf(mnv, v);
        s += v; ss = fmaf(v, v, ss);
    }
    int n = blockIdx.x * 4 + a;
    Mx[n * 64 + o] = mxv;
    Mn[n * 64 + o] = mnv;
    float* sred = &Ws[0][0];
    float* ssred = sred + 256;
    sred[a * 64 + o] = s;
    ssred[a * 64 + o] = ss;
    __syncthreads();
    if (tid < 64) {
        float ts = sred[tid] + sred[64 + tid] + sred[128 + tid] + sred[192 + tid];
        float tss = ssred[tid] + ssred[64 + tid] + ssred[128 + tid] + ssred[192 + tid];
        float* gg = gsOut + (blockIdx.x & (NREP - 1)) * 128;
        atomicAdd(gg + tid, ts);
        atomicAdd(gg + 64 + tid, tss);
    }
}

// ---------------------------------------------------------------- pool + next-stage projection
__global__ __launch_bounds__(256) void pool_proj_kernel(const float* __restrict__ Mx,
                                                        const float* __restrict__ Mn,
                                                        const float* __restrict__ gsIn,
                                                        const float* __restrict__ g,
                                                        const float* __restrict__ b,
                                                        const float* __restrict__ Wt,
                                                        float* __restrict__ Xout,
                                                        float* __restrict__ Pout) {
    __shared__ float saff[128];
    __shared__ float xs[4][64];
    int tid = threadIdx.x;
    compute_affine(gsIn, g, b, saff, tid);
    __syncthreads();
    int n0 = blockIdx.x * 4;
    int pp = tid >> 6, o = tid & 63;
    float sc = saff[o], sh = saff[64 + o];
    float v = (sc >= 0.f) ? Mx[(n0 + pp) * 64 + o] : Mn[(n0 + pp) * 64 + o];
    float xv = lrelu(fmaf(v, sc, sh));
    Xout[(n0 + pp) * 64 + o] = xv;
    xs[pp][o] = xv;
    __syncthreads();
    int o2 = tid & 127, h = tid >> 7;
    int p0 = h * 2, p1 = h * 2 + 1;
    float a0 = 0.f, a1 = 0.f;
    for (int c = 0; c < 64; ++c) {
        float w = Wt[c * 128 + o2];
        a0 = fmaf(xs[p0][c], w, a0);
        a1 = fmaf(xs[p1][c], w, a1);
    }
    Pout[(n0 + p0) * 128 + o2] = a0;
    Pout[(n0 + p1) * 128 + o2] = a1;
}

// ---------------------------------------------------------------- fused final MLP (+ inline stage-3 edge+pool)
__global__ __launch_bounds__(128) void mlp_kernel(const float* __restrict__ x1,
                                                  const float* __restrict__ x2,
                                                  const float* __restrict__ P,
                                                  const int* __restrict__ idx,
                                                  const float* __restrict__ gs5,
                                                  const float* __restrict__ g5,
                                                  const float* __restrict__ b5,
                                                  const float* __restrict__ W9at,
                                                  const float* __restrict__ b9a,
                                                  const float* __restrict__ W9bt,
                                                  const float* __restrict__ b9b,
                                                  float* __restrict__ out) {
    __shared__ float saff[128];
    __shared__ float xs3[8][64];
    __shared__ float hs[8][128];
    int tid = threadIdx.x;
    compute_affine(gs5, g5, b5, saff, tid);
    __syncthreads();
    int n0 = blockIdx.x * 8;
    // inline zpool: compute x3 for this block's 8 points (2 waves x 4 points each)
    {
        int o = tid & 63;
        for (int pp = (tid >> 6); pp < 8; pp += 2) {
            int n = n0 + pp;
            float An = P[n * 128 + o];
            float Bn = P[n * 128 + 64 + o];
            float base = Bn - An;
            float mxz = -INFINITY, mnz = INFINITY;
#pragma unroll
            for (int kk = 0; kk < KNN; ++kk) {
                int m = idx[n * KNN + kk];
                float z = P[(size_t)m * 128 + o] + base;
                mxz = fmaxf(mxz, z); mnz = fminf(mnz, z);
            }
            float sc = saff[o], sh = saff[64 + o];
            float v = (sc >= 0.f) ? mxz : mnz;
            xs3[pp][o] = lrelu(fmaf(v, sc, sh));
        }
    }
    __syncthreads();

    int j = tid;
    float acc[8];
    float bj = b9a[j];
#pragma unroll
    for (int p = 0; p < 8; ++p) acc[p] = bj;
    for (int c = 0; c < 64; ++c) {
        float w = W9at[c * 128 + j];
#pragma unroll
        for (int p = 0; p < 8; ++p) acc[p] = fmaf(x1[(n0 + p) * 64 + c], w, acc[p]);
    }
    for (int c = 0; c < 64; ++c) {
        float w = W9at[(64 + c) * 128 + j];
#pragma unroll
        for (int p = 0; p < 8; ++p) acc[p] = fmaf(x2[(n0 + p) * 64 + c], w, acc[p]);
    }
    for (int c = 0; c < 64; ++c) {
        float w = W9at[(128 + c) * 128 + j];
#pragma unroll
        for (int p = 0; p < 8; ++p) acc[p] = fmaf(xs3[p][c], w, acc[p]);
    }
#pragma unroll
    for (int p = 0; p < 8; ++p) hs[p][j] = fmaxf(acc[p], 0.f);
    __syncthreads();
    int p2 = tid >> 4, j2 = tid & 15;
    float a = b9b[j2];
    for (int c = 0; c < 128; ++c) a = fmaf(hs[p2][c], W9bt[c * 16 + j2], a);
    out[j2 * NPTS + n0 + p2] = a;
}

// ---------------------------------------------------------------- launch
extern "C" void kernel_launch(void* const* d_in, const int* in_sizes, int n_in,
                              void* d_out, int out_size, void* d_ws, size_t ws_size,
                              hipStream_t stream) {
    const float* x   = (const float*)d_in[0];
    const float* W1  = (const float*)d_in[2];
    const float* g1  = (const float*)d_in[3];
    const float* b1  = (const float*)d_in[4];
    const float* W2  = (const float*)d_in[5];
    const float* g2  = (const float*)d_in[6];
    const float* b2  = (const float*)d_in[7];
    const float* W3  = (const float*)d_in[8];
    const float* g3  = (const float*)d_in[9];
    const float* b3  = (const float*)d_in[10];
    const float* W4  = (const float*)d_in[11];
    const float* g4  = (const float*)d_in[12];
    const float* b4  = (const float*)d_in[13];
    const float* W5  = (const float*)d_in[14];
    const float* g5  = (const float*)d_in[15];
    const float* b5  = (const float*)d_in[16];
    const float* W9a = (const float*)d_in[17];
    const float* b9a = (const float*)d_in[18];
    const float* W9b = (const float*)d_in[19];
    const float* b9b = (const float*)d_in[20];
    float* out = (float*)d_out;

    char* ws = (char*)d_ws;
    int*    idx    = (int*)(ws + 0);                 // 655360
    float4* pk     = (float4*)(ws + 655360);         // 131072
    float*  P      = (float*)(ws + 786432);          // 4 MB
    float*  Mx     = (float*)(ws + 4980736);         // 2 MB
    float*  Mn     = (float*)(ws + 7077888);         // 2 MB
    float*  gsAll  = (float*)(ws + 9175040);         // 163840
    float*  x1b    = (float*)(ws + 9338880);         // 2 MB
    float*  x2b    = (float*)(ws + 11436032);        // 2 MB
    float*  Wt1    = (float*)(ws + 15630336);        // 34304
    float*  Wt3    = (float*)(ws + 15664640);        // 32768
    float*  Wt5    = (float*)(ws + 15697408);        // 32768
    float*  W9at   = (float*)(ws + 15730176);        // 98304
    float*  W9bt   = (float*)(ws + 15828480);        // 8192
    float*  theta  = (float*)(ws + 15836672);        // 32768
    (void)ws_size; (void)in_sizes; (void)n_in; (void)out_size;

    float* gs1 = gsAll;
    float* gs2 = gsAll + 1 * NREP * 128;
    float* gs3 = gsAll + 2 * NREP * 128;
    float* gs4 = gsAll + 3 * NREP * 128;
    float* gs5 = gsAll + 4 * NREP * 128;

    prep_kernel<<<394, 256, 0, stream>>>(x, W1, W3, W5, W9a, W9b, pk, Wt1, Wt3, Wt5, W9at, W9bt, gsAll);
    knn_theta_proj<<<1536, 256, 0, stream>>>(pk, theta, x, Wt1, P);
    knn_fsel<<<NPTS / 8, 512, 0, stream>>>(pk, theta, idx, P, gs1);

    // stage 1
    conv_gemm_kernel<<<NPTS * KNN / 80, 256, 0, stream>>>(P, idx, gs1, g1, b1, W2, gs2, Mx, Mn);
    pool_proj_kernel<<<NPTS / 4, 256, 0, stream>>>(Mx, Mn, gs2, g2, b2, Wt3, x1b, P);

    // stage 2
    zsum_kernel<<<NPTS / 4, 256, 0, stream>>>(P, idx, gs3);
    conv_gemm_kernel<<<NPTS * KNN / 80, 256, 0, stream>>>(P, idx, gs3, g3, b3, W4, gs4, Mx, Mn);
    pool_proj_kernel<<<NPTS / 4, 256, 0, stream>>>(Mx, Mn, gs4, g4, b4, Wt5, x2b, P);

    // stage 3: zsum for BN stats, then mlp computes edge+pool inline
    zsum_kernel<<<NPTS / 4, 256, 0, stream>>>(P, idx, gs5);
    mlp_kernel<<<NPTS / 8, 128, 0, stream>>>(x1b, x2b, P, idx, gs5, g5, b5, W9at, b9a, W9bt, b9b, out);
}

// Round 24
// 210.979 us; speedup vs baseline: 1.1421x; 1.0027x over previous
//
#include <hip/hip_runtime.h>

#define NPTS 8192
#define KNN  20
#define NREP 64
#define THSUB 2048
#define FCAP 256

__device__ __forceinline__ float pair_dist4(float qx, float qy, float qz, float xxn, float4 c) {
    float dot = fmaf(qz, c.z, fmaf(qy, c.y, qx * c.x));
    return fmaf(2.f, dot, -xxn) - c.w;
}
__device__ __forceinline__ float self_sq(float dx, float dy, float dz) {
    return fmaf(dz, dz, fmaf(dy, dy, dx * dx));
}
__device__ __forceinline__ float lrelu(float v) { return (v >= 0.f) ? v : 0.2f * v; }

__device__ __forceinline__ void compute_affine(const float* __restrict__ gs,
                                               const float* __restrict__ g,
                                               const float* __restrict__ b,
                                               float* saff, int tid) {
    if (tid < 64) {
        float s = 0.f, ss = 0.f;
        for (int r = 0; r < NREP; ++r) { s += gs[r * 128 + tid]; ss += gs[r * 128 + 64 + tid]; }
        const float invM = 1.f / (float)(NPTS * KNN);
        float mean = s * invM;
        float var = ss * invM - mean * mean;
        float sc = g[tid] * rsqrtf(var + 1e-5f);
        saff[tid] = sc;
        saff[64 + tid] = b[tid] - mean * sc;
    }
}

// ---------------------------------------------------------------- prep (zeroes gsAll)
__global__ __launch_bounds__(256) void prep_kernel(const float* __restrict__ x,
                                                   const float* __restrict__ W1,
                                                   const float* __restrict__ W3,
                                                   const float* __restrict__ W5,
                                                   const float* __restrict__ W9a,
                                                   const float* __restrict__ W9b,
                                                   float4* __restrict__ pk,
                                                   float* __restrict__ Wt1,
                                                   float* __restrict__ Wt3,
                                                   float* __restrict__ Wt5,
                                                   float* __restrict__ W9at,
                                                   float* __restrict__ W9bt,
                                                   float* __restrict__ gsAll) {
    int gid = blockIdx.x * 256 + threadIdx.x;
    if (gid < NPTS) {
        float dx = x[64 * NPTS + gid], dy = x[65 * NPTS + gid], dz = x[66 * NPTS + gid];
        pk[gid] = make_float4(dx, dy, dz, self_sq(dx, dy, dz));
        return;
    }
    gid -= NPTS;
    if (gid < 67 * 128) {
        int c = gid >> 7, o = gid & 127;
        Wt1[gid] = (o < 64) ? W1[o * 134 + c] : W1[(o - 64) * 134 + 67 + c];
        return;
    }
    gid -= 67 * 128;
    if (gid < 64 * 128) {
        int c = gid >> 7, o = gid & 127;
        Wt3[gid] = (o < 64) ? W3[o * 128 + c] : W3[(o - 64) * 128 + 64 + c];
        return;
    }
    gid -= 64 * 128;
    if (gid < 64 * 128) {
        int c = gid >> 7, o = gid & 127;
        Wt5[gid] = (o < 64) ? W5[o * 128 + c] : W5[(o - 64) * 128 + 64 + c];
        return;
    }
    gid -= 64 * 128;
    if (gid < 192 * 128) {
        int c = gid >> 7, j = gid & 127;
        W9at[gid] = W9a[j * 192 + c];
        return;
    }
    gid -= 192 * 128;
    if (gid < 128 * 16) {
        int c = gid >> 4, j = gid & 15;
        W9bt[gid] = W9b[j * 128 + c];
        return;
    }
    gid -= 128 * 16;
    if (gid < 5 * NREP * 128) gsAll[gid] = 0.f;
}

// ---------------------------------------------------------------- kNN theta (2048-subset) + stage-1 proj
__global__ __launch_bounds__(256) void knn_theta_proj(const float4* __restrict__ pk,
                                                      float* __restrict__ theta,
                                                      const float* __restrict__ X,
                                                      const float* __restrict__ Wt1,
                                                      float* __restrict__ P) {
    __shared__ float4 cpt[THSUB];
    int tid = threadIdx.x;
    if (blockIdx.x >= 512) {
        int bb = blockIdx.x - 512;
        int o = tid & 127, h = tid >> 7;
        int n0 = bb * 8 + h * 4;
        float acc[4] = {0.f, 0.f, 0.f, 0.f};
        for (int c = 0; c < 67; ++c) {
            float w = Wt1[c * 128 + o];
#pragma unroll
            for (int i = 0; i < 4; ++i) acc[i] = fmaf(X[(n0 + i) + c * NPTS], w, acc[i]);
        }
#pragma unroll
        for (int i = 0; i < 4; ++i) P[(n0 + i) * 128 + o] = acc[i];
        return;
    }
    int wid = tid >> 6, lane = tid & 63;
    int qbase = blockIdx.x * 16 + wid * 4;
    for (int i = tid; i < THSUB; i += 256) cpt[i] = pk[i];
    float qx[4], qy[4], qz[4], xxn[4], mv[4];
#pragma unroll
    for (int qi = 0; qi < 4; ++qi) {
        float4 qp = pk[qbase + qi];
        qx[qi] = qp.x; qy[qi] = qp.y; qz[qi] = qp.z; xxn[qi] = qp.w;
        mv[qi] = -INFINITY;
    }
    __syncthreads();
    for (int t = 0; t < THSUB / 64; ++t) {
        float4 c = cpt[t * 64 + lane];
#pragma unroll
        for (int qi = 0; qi < 4; ++qi)
            mv[qi] = fmaxf(mv[qi], pair_dist4(qx[qi], qy[qi], qz[qi], xxn[qi], c));
    }
    // theta = 20th largest of 64 disjoint lane maxima over the subset => theta <= v20(full set)
#pragma unroll 1
    for (int qi = 0; qi < 4; ++qi) {
        float sel = mv[qi];
        float th = -INFINITY;
        for (int r = 0; r < KNN; ++r) {
            float v = sel;
#pragma unroll
            for (int m = 32; m >= 1; m >>= 1) v = fmaxf(v, __shfl_xor(v, m));
            th = v;
            unsigned long long bm = __ballot(sel == v);
            if (lane == __ffsll(bm) - 1) sel = -INFINITY;
        }
        if (lane == 0) theta[qbase + qi] = th - 1e-3f;
    }
}

// ---------------------------------------------------------------- fused filter + select + zsum1
// 8 queries/block (512 thr, 8 waves), 1 query/wave; 2048-pt staging chunks (8 barriers total).
__global__ __launch_bounds__(512) void knn_fsel(const float4* __restrict__ pk,
                                                const float* __restrict__ theta,
                                                int* __restrict__ idx_out,
                                                const float* __restrict__ P,
                                                float* __restrict__ gs) {
    __shared__ float4 cpt[2048];
    __shared__ int bufi[8][FCAP];
    int tid = threadIdx.x, wid = tid >> 6, lane = tid & 63;
    int q = blockIdx.x * 8 + wid;
    float4 qp = pk[q];
    float th = theta[q];
    int wcnt = 0;
    unsigned long long below = (1ull << lane) - 1ull;

    for (int ch = 0; ch < 4; ++ch) {
        __syncthreads();
        for (int i = tid; i < 2048; i += 512) cpt[i] = pk[ch * 2048 + i];
        __syncthreads();
        for (int t = 0; t < 32; ++t) {
            int gi = ch * 2048 + t * 64 + lane;
            float4 c = cpt[t * 64 + lane];
            float d = pair_dist4(qp.x, qp.y, qp.z, qp.w, c);
            bool p = (d >= th);
            unsigned long long mk = __ballot(p);
            if (p) {
                int pos = wcnt + (int)__popcll(mk & below);
                if (pos < FCAP) bufi[wid][pos] = gi;
            }
            wcnt += (int)__popcll(mk);
        }
    }
    // no block barrier needed: each wave reads only its own bufi row

    int mi_keep = 0;
    if (wcnt <= FCAP) {
        float sv[4]; int si[4];
#pragma unroll
        for (int r = 0; r < 4; ++r) {
            int j = r * 64 + lane;
            bool ok = j < wcnt;
            int sidx = ok ? bufi[wid][j] : 0;
            float dv = pair_dist4(qp.x, qp.y, qp.z, qp.w, pk[sidx]);
            sv[r] = ok ? dv : -INFINITY;
            si[r] = ok ? sidx : 0x7fffffff;
        }
        for (int r = 0; r < KNN; ++r) {
            float lv = -INFINITY; int li = 0x7fffffff; int ls = -1;
#pragma unroll
            for (int s3 = 0; s3 < 4; ++s3) {
                bool g = (sv[s3] > lv) || (sv[s3] == lv && si[s3] < li);
                if (g) { lv = sv[s3]; li = si[s3]; ls = s3; }
            }
            float wv = lv; int wi = li;
#pragma unroll
            for (int m = 32; m >= 1; m >>= 1) {
                float ov = __shfl_xor(wv, m); int oi = __shfl_xor(wi, m);
                if (ov > wv || (ov == wv && oi < wi)) { wv = ov; wi = oi; }
            }
            if (lv == wv && li == wi) {
#pragma unroll
                for (int s3 = 0; s3 < 4; ++s3)
                    if (s3 == ls) { sv[s3] = -INFINITY; si[s3] = 0x7fffffff; }
            }
            if (lane == 0) idx_out[q * KNN + r] = wi;
            if (lane == r) mi_keep = wi;
        }
    } else {
        // exact fallback: 20-round lex-max scan over all points (rare)
        float pv = INFINITY; int pi = -1;
        for (int r = 0; r < KNN; ++r) {
            float bv = -INFINITY; int bi = 0x7fffffff;
            for (int t = 0; t < NPTS / 64; ++t) {
                int i = t * 64 + lane;
                float d = pair_dist4(qp.x, qp.y, qp.z, qp.w, pk[i]);
                bool adm = (d < pv) || (d == pv && i > pi);
                if (adm && (d > bv || (d == bv && i < bi))) { bv = d; bi = i; }
            }
            float wv = bv; int wi = bi;
#pragma unroll
            for (int m = 32; m >= 1; m >>= 1) {
                float ov = __shfl_xor(wv, m); int oi = __shfl_xor(wi, m);
                if (ov > wv || (ov == wv && oi < wi)) { wv = ov; wi = oi; }
            }
            if (lane == 0) idx_out[q * KNN + r] = wi;
            if (lane == r) mi_keep = wi;
            pv = wv; pi = wi;
        }
    }
    // fused zsum for this query (o = lane)
    float An = P[q * 128 + lane];
    float Bn = P[q * 128 + 64 + lane];
    float base = Bn - An;
    float sum = 0.f, ss = 0.f;
#pragma unroll
    for (int kk = 0; kk < KNN; ++kk) {
        int m = __shfl(mi_keep, kk);
        float z = P[(size_t)m * 128 + lane] + base;
        sum += z;
        ss = fmaf(z, z, ss);
    }
    float* gg = gs + (blockIdx.x & (NREP - 1)) * 128;
    atomicAdd(gg + lane, sum);
    atomicAdd(gg + 64 + lane, ss);
}

// ---------------------------------------------------------------- z stats (stages 2,3)
__global__ __launch_bounds__(256) void zsum_kernel(const float* __restrict__ P,
                                                   const int* __restrict__ idx,
                                                   float* __restrict__ gs) {
    int tid = threadIdx.x;
    int o = tid & 63;
    float sum = 0.f, sumsq = 0.f;
    int n0 = blockIdx.x * 4;
#pragma unroll
    for (int ni = 0; ni < 4; ++ni) {
        int n = n0 + ni;
        float An = P[n * 128 + o];
        float Bn = P[n * 128 + 64 + o];
        float base = Bn - An;
#pragma unroll
        for (int kk2 = 0; kk2 < 5; ++kk2) {
            int kk = (tid >> 6) + kk2 * 4;
            int m = idx[n * KNN + kk];
            float z = P[m * 128 + o] + base;
            sum += z;
            sumsq = fmaf(z, z, sumsq);
        }
    }
    __shared__ float s1[256], s2[256];
    s1[tid] = sum; s2[tid] = sumsq;
    __syncthreads();
    if (tid < 64) {
        float a = s1[tid] + s1[tid + 64] + s1[tid + 128] + s1[tid + 192];
        float b = s2[tid] + s2[tid + 64] + s2[tid + 128] + s2[tid + 192];
        float* g = gs + (blockIdx.x & (NREP - 1)) * 128;
        atomicAdd(g + tid, a);
        atomicAdd(g + 64 + tid, b);
    }
}

// ---------------------------------------------------------------- conv GEMM: 80-row n-aligned tile
__global__ __launch_bounds__(256) void conv_gemm_kernel(const float* __restrict__ P,
                                                        const int* __restrict__ idx,
                                                        const float* __restrict__ gsIn,
                                                        const float* __restrict__ gIn,
                                                        const float* __restrict__ bIn,
                                                        const float* __restrict__ W,
                                                        float* __restrict__ gsOut,
                                                        float* __restrict__ Mx,
                                                        float* __restrict__ Mn) {
    __shared__ float As[80][68];
    __shared__ float Ws[64][68];
    __shared__ float saff[128];
    int tid = threadIdx.x;
    int r0 = blockIdx.x * 80;

    compute_affine(gsIn, gIn, bIn, saff, tid);
    for (int i2 = tid; i2 < 1024; i2 += 256) {
        int rr = i2 >> 4, c4 = (i2 & 15) * 4;
        *(float4*)&Ws[rr][c4] = *(const float4*)&W[rr * 64 + c4];
    }
    __syncthreads();

#pragma unroll 5
    for (int i2 = tid; i2 < 1280; i2 += 256) {
        int rr = i2 >> 4, c4 = (i2 & 15) * 4;
        int grow = r0 + rr;
        int n = grow / 20;
        int m = idx[grow];
        float4 zn = *(const float4*)&P[(size_t)m * 128 + c4];
        float4 an = *(const float4*)&P[(size_t)n * 128 + c4];
        float4 bn = *(const float4*)&P[(size_t)n * 128 + 64 + c4];
        float4 ov; float z;
        z = zn.x + (bn.x - an.x); ov.x = lrelu(fmaf(z, saff[c4 + 0], saff[64 + c4 + 0]));
        z = zn.y + (bn.y - an.y); ov.y = lrelu(fmaf(z, saff[c4 + 1], saff[64 + c4 + 1]));
        z = zn.z + (bn.z - an.z); ov.z = lrelu(fmaf(z, saff[c4 + 2], saff[64 + c4 + 2]));
        z = zn.w + (bn.w - an.w); ov.w = lrelu(fmaf(z, saff[c4 + 3], saff[64 + c4 + 3]));
        *(float4*)&As[rr][c4] = ov;
    }
    __syncthreads();

    int ty = tid >> 4, tx = tid & 15;
    float acc[5][4];
#pragma unroll
    for (int i = 0; i < 5; ++i)
#pragma unroll
        for (int j = 0; j < 4; ++j) acc[i][j] = 0.f;

    for (int c4 = 0; c4 < 64; c4 += 4) {
        float4 a4[5], w4[4];
#pragma unroll
        for (int i = 0; i < 5; ++i) a4[i] = *(const float4*)&As[ty + 16 * i][c4];
#pragma unroll
        for (int j = 0; j < 4; ++j) w4[j] = *(const float4*)&Ws[tx + 16 * j][c4];
#pragma unroll
        for (int i = 0; i < 5; ++i)
#pragma unroll
            for (int j = 0; j < 4; ++j) {
                acc[i][j] = fmaf(a4[i].x, w4[j].x, acc[i][j]);
                acc[i][j] = fmaf(a4[i].y, w4[j].y, acc[i][j]);
                acc[i][j] = fmaf(a4[i].z, w4[j].z, acc[i][j]);
                acc[i][j] = fmaf(a4[i].w, w4[j].w, acc[i][j]);
            }
    }
    __syncthreads();

#pragma unroll
    for (int i = 0; i < 5; ++i)
#pragma unroll
        for (int j = 0; j < 4; ++j) As[ty + 16 * i][tx + 16 * j] = acc[i][j];
    __syncthreads();

    int a = tid >> 6, o = tid & 63;
    float mxv = -INFINITY, mnv = INFINITY, s = 0.f, ss = 0.f;
#pragma unroll
    for (int r = 0; r < 20; ++r) {
        float v = As[20 * a + r][o];
        mxv = fmaxf(mxv, v); mnv = fminf(mnv, v);
        s += v; ss = fmaf(v, v, ss);
    }
    int n = blockIdx.x * 4 + a;
    Mx[n * 64 + o] = mxv;
    Mn[n * 64 + o] = mnv;
    float* sred = &Ws[0][0];
    float* ssred = sred + 256;
    sred[a * 64 + o] = s;
    ssred[a * 64 + o] = ss;
    __syncthreads();
    if (tid < 64) {
        float ts = sred[tid] + sred[64 + tid] + sred[128 + tid] + sred[192 + tid];
        float tss = ssred[tid] + ssred[64 + tid] + ssred[128 + tid] + ssred[192 + tid];
        float* gg = gsOut + (blockIdx.x & (NREP - 1)) * 128;
        atomicAdd(gg + tid, ts);
        atomicAdd(gg + 64 + tid, tss);
    }
}

// ---------------------------------------------------------------- pool + next-stage projection
__global__ __launch_bounds__(256) void pool_proj_kernel(const float* __restrict__ Mx,
                                                        const float* __restrict__ Mn,
                                                        const float* __restrict__ gsIn,
                                                        const float* __restrict__ g,
                                                        const float* __restrict__ b,
                                                        const float* __restrict__ Wt,
                                                        float* __restrict__ Xout,
                                                        float* __restrict__ Pout) {
    __shared__ float saff[128];
    __shared__ float xs[4][64];
    int tid = threadIdx.x;
    compute_affine(gsIn, g, b, saff, tid);
    __syncthreads();
    int n0 = blockIdx.x * 4;
    int pp = tid >> 6, o = tid & 63;
    float sc = saff[o], sh = saff[64 + o];
    float v = (sc >= 0.f) ? Mx[(n0 + pp) * 64 + o] : Mn[(n0 + pp) * 64 + o];
    float xv = lrelu(fmaf(v, sc, sh));
    Xout[(n0 + pp) * 64 + o] = xv;
    xs[pp][o] = xv;
    __syncthreads();
    int o2 = tid & 127, h = tid >> 7;
    int p0 = h * 2, p1 = h * 2 + 1;
    float a0 = 0.f, a1 = 0.f;
    for (int c = 0; c < 64; ++c) {
        float w = Wt[c * 128 + o2];
        a0 = fmaf(xs[p0][c], w, a0);
        a1 = fmaf(xs[p1][c], w, a1);
    }
    Pout[(n0 + p0) * 128 + o2] = a0;
    Pout[(n0 + p1) * 128 + o2] = a1;
}

// ---------------------------------------------------------------- fused final MLP (+ inline stage-3 edge+pool)
__global__ __launch_bounds__(128) void mlp_kernel(const float* __restrict__ x1,
                                                  const float* __restrict__ x2,
                                                  const float* __restrict__ P,
                                                  const int* __restrict__ idx,
                                                  const float* __restrict__ gs5,
                                                  const float* __restrict__ g5,
                                                  const float* __restrict__ b5,
                                                  const float* __restrict__ W9at,
                                                  const float* __restrict__ b9a,
                                                  const float* __restrict__ W9bt,
                                                  const float* __restrict__ b9b,
                                                  float* __restrict__ out) {
    __shared__ float saff[128];
    __shared__ float xs3[8][64];
    __shared__ float hs[8][128];
    int tid = threadIdx.x;
    compute_affine(gs5, g5, b5, saff, tid);
    __syncthreads();
    int n0 = blockIdx.x * 8;
    // inline zpool: compute x3 for this block's 8 points (2 waves x 4 points each)
    {
        int o = tid & 63;
        for (int pp = (tid >> 6); pp < 8; pp += 2) {
            int n = n0 + pp;
            float An = P[n * 128 + o];
            float Bn = P[n * 128 + 64 + o];
            float base = Bn - An;
            float mxz = -INFINITY, mnz = INFINITY;
#pragma unroll
            for (int kk = 0; kk < KNN; ++kk) {
                int m = idx[n * KNN + kk];
                float z = P[(size_t)m * 128 + o] + base;
                mxz = fmaxf(mxz, z); mnz = fminf(mnz, z);
            }
            float sc = saff[o], sh = saff[64 + o];
            float v = (sc >= 0.f) ? mxz : mnz;
            xs3[pp][o] = lrelu(fmaf(v, sc, sh));
        }
    }
    __syncthreads();

    int j = tid;
    float acc[8];
    float bj = b9a[j];
#pragma unroll
    for (int p = 0; p < 8; ++p) acc[p] = bj;
    for (int c = 0; c < 64; ++c) {
        float w = W9at[c * 128 + j];
#pragma unroll
        for (int p = 0; p < 8; ++p) acc[p] = fmaf(x1[(n0 + p) * 64 + c], w, acc[p]);
    }
    for (int c = 0; c < 64; ++c) {
        float w = W9at[(64 + c) * 128 + j];
#pragma unroll
        for (int p = 0; p < 8; ++p) acc[p] = fmaf(x2[(n0 + p) * 64 + c], w, acc[p]);
    }
    for (int c = 0; c < 64; ++c) {
        float w = W9at[(128 + c) * 128 + j];
#pragma unroll
        for (int p = 0; p < 8; ++p) acc[p] = fmaf(xs3[p][c], w, acc[p]);
    }
#pragma unroll
    for (int p = 0; p < 8; ++p) hs[p][j] = fmaxf(acc[p], 0.f);
    __syncthreads();
    int p2 = tid >> 4, j2 = tid & 15;
    float a = b9b[j2];
    for (int c = 0; c < 128; ++c) a = fmaf(hs[p2][c], W9bt[c * 16 + j2], a);
    out[j2 * NPTS + n0 + p2] = a;
}

// ---------------------------------------------------------------- launch
extern "C" void kernel_launch(void* const* d_in, const int* in_sizes, int n_in,
                              void* d_out, int out_size, void* d_ws, size_t ws_size,
                              hipStream_t stream) {
    const float* x   = (const float*)d_in[0];
    const float* W1  = (const float*)d_in[2];
    const float* g1  = (const float*)d_in[3];
    const float* b1  = (const float*)d_in[4];
    const float* W2  = (const float*)d_in[5];
    const float* g2  = (const float*)d_in[6];
    const float* b2  = (const float*)d_in[7];
    const float* W3  = (const float*)d_in[8];
    const float* g3  = (const float*)d_in[9];
    const float* b3  = (const float*)d_in[10];
    const float* W4  = (const float*)d_in[11];
    const float* g4  = (const float*)d_in[12];
    const float* b4  = (const float*)d_in[13];
    const float* W5  = (const float*)d_in[14];
    const float* g5  = (const float*)d_in[15];
    const float* b5  = (const float*)d_in[16];
    const float* W9a = (const float*)d_in[17];
    const float* b9a = (const float*)d_in[18];
    const float* W9b = (const float*)d_in[19];
    const float* b9b = (const float*)d_in[20];
    float* out = (float*)d_out;

    char* ws = (char*)d_ws;
    int*    idx    = (int*)(ws + 0);                 // 655360
    float4* pk     = (float4*)(ws + 655360);         // 131072
    float*  P      = (float*)(ws + 786432);          // 4 MB
    float*  Mx     = (float*)(ws + 4980736);         // 2 MB
    float*  Mn     = (float*)(ws + 7077888);         // 2 MB
    float*  gsAll  = (float*)(ws + 9175040);         // 163840
    float*  x1b    = (float*)(ws + 9338880);         // 2 MB
    float*  x2b    = (float*)(ws + 11436032);        // 2 MB
    float*  Wt1    = (float*)(ws + 15630336);        // 34304
    float*  Wt3    = (float*)(ws + 15664640);        // 32768
    float*  Wt5    = (float*)(ws + 15697408);        // 32768
    float*  W9at   = (float*)(ws + 15730176);        // 98304
    float*  W9bt   = (float*)(ws + 15828480);        // 8192
    float*  theta  = (float*)(ws + 15836672);        // 32768
    (void)ws_size; (void)in_sizes; (void)n_in; (void)out_size;

    float* gs1 = gsAll;
    float* gs2 = gsAll + 1 * NREP * 128;
    float* gs3 = gsAll + 2 * NREP * 128;
    float* gs4 = gsAll + 3 * NREP * 128;
    float* gs5 = gsAll + 4 * NREP * 128;

    prep_kernel<<<394, 256, 0, stream>>>(x, W1, W3, W5, W9a, W9b, pk, Wt1, Wt3, Wt5, W9at, W9bt, gsAll);
    knn_theta_proj<<<1536, 256, 0, stream>>>(pk, theta, x, Wt1, P);
    knn_fsel<<<NPTS / 8, 512, 0, stream>>>(pk, theta, idx, P, gs1);

    // stage 1
    conv_gemm_kernel<<<NPTS * KNN / 80, 256, 0, stream>>>(P, idx, gs1, g1, b1, W2, gs2, Mx, Mn);
    pool_proj_kernel<<<NPTS / 4, 256, 0, stream>>>(Mx, Mn, gs2, g2, b2, Wt3, x1b, P);

    // stage 2
    zsum_kernel<<<NPTS / 4, 256, 0, stream>>>(P, idx, gs3);
    conv_gemm_kernel<<<NPTS * KNN / 80, 256, 0, stream>>>(P, idx, gs3, g3, b3, W4, gs4, Mx, Mn);
    pool_proj_kernel<<<NPTS / 4, 256, 0, stream>>>(Mx, Mn, gs4, g4, b4, Wt5, x2b, P);

    // stage 3: zsum for BN stats, then mlp computes edge+pool inline
    zsum_kernel<<<NPTS / 4, 256, 0, stream>>>(P, idx, gs5);
    mlp_kernel<<<NPTS / 8, 128, 0, stream>>>(x1b, x2b, P, idx, gs5, g5, b5, W9at, b9a, W9bt, b9b, out);
}